// Round 4
// baseline (255.445 us; speedup 1.0000x reference)
//
#include <hip/hip_runtime.h>

#define N_L 256
#define N_Q 65536
#define D_IN 384
#define D_CTX 192
#define HDIM 64
#define MAXA 6

typedef float v2f __attribute__((ext_vector_type(2)));

__device__ __forceinline__ v2f mk2(float a, float b) { v2f r; r.x = a; r.y = b; return r; }

__device__ __forceinline__ void fma4(float& acc, const float4& w, const float4& v) {
    acc = fmaf(w.x, v.x, acc);
    acc = fmaf(w.y, v.y, acc);
    acc = fmaf(w.z, v.z, acc);
    acc = fmaf(w.w, v.w, acc);
}

__device__ __forceinline__ float lgfact(int n) {
    // log(n!) for n in 0..6  (== gammaln(n+1))
    return (n <= 1) ? 0.0f :
           (n == 2) ? 0.6931471805599453f :
           (n == 3) ? 1.7917594692280550f :
           (n == 4) ? 3.1780538303479458f :
           (n == 5) ? 4.7874917427820460f :
                      6.5792512120101010f;
}

// ---------------- DPP wave reduction helpers (VALU pipe, no LDS traffic) ----------------
template<int CTRL, int RM, bool BC>
__device__ __forceinline__ float dppz(float x) {   // old = 0 (masked/invalid lanes contribute 0)
    return __int_as_float(__builtin_amdgcn_update_dpp(0, __float_as_int(x), CTRL, RM, 0xF, BC));
}
template<int CTRL, int RM>
__device__ __forceinline__ float dpps(float x) {   // old = x (identity for max)
    int xi = __float_as_int(x);
    return __int_as_float(__builtin_amdgcn_update_dpp(xi, xi, CTRL, RM, 0xF, false));
}
// inclusive prefix-sum across 64 lanes; lane 63 ends with the wave total
__device__ __forceinline__ float wave_iscan(float t) {
    t += dppz<0x111, 0xF, true>(t);    // row_shr:1, 0-fill
    t += dppz<0x112, 0xF, true>(t);    // row_shr:2
    t += dppz<0x114, 0xF, true>(t);    // row_shr:4
    t += dppz<0x118, 0xF, true>(t);    // row_shr:8
    t += dppz<0x142, 0xA, false>(t);   // row_bcast:15 -> rows 1,3
    t += dppz<0x143, 0xC, false>(t);   // row_bcast:31 -> rows 2,3
    return t;
}
// wave max; lane 63 ends with the full 64-lane max (exact, max is associative)
__device__ __forceinline__ float wave_max_l63(float m) {
    m = fmaxf(m, dpps<0x111, 0xF>(m));
    m = fmaxf(m, dpps<0x112, 0xF>(m));
    m = fmaxf(m, dpps<0x114, 0xF>(m));
    m = fmaxf(m, dpps<0x118, 0xF>(m));
    m = fmaxf(m, dpps<0x142, 0xA>(m));
    m = fmaxf(m, dpps<0x143, 0xC>(m));
    return m;
}
__device__ __forceinline__ float bc63(float x) {   // broadcast lane 63 via SGPR
    return __int_as_float(__builtin_amdgcn_readlane(__float_as_int(x), 63));
}

// ---------------- packed fp32 FMA with op_sel broadcast of one half of src1 ----------------
// d.lo += a.lo * b.lo ; d.hi += a.hi * b.lo
__device__ __forceinline__ void pk_fma_lo(v2f& d, v2f a, v2f b) {
    asm("v_pk_fma_f32 %0, %1, %2, %0 op_sel:[0,0,0] op_sel_hi:[1,0,1]"
        : "+v"(d) : "v"(a), "v"(b));
}
// d.lo += a.lo * b.hi ; d.hi += a.hi * b.hi
__device__ __forceinline__ void pk_fma_hi(v2f& d, v2f a, v2f b) {
    asm("v_pk_fma_f32 %0, %1, %2, %0 op_sel:[0,1,0] op_sel_hi:[1,1,1]"
        : "+v"(d) : "v"(a), "v"(b));
}

// ---------------- Kernel 1: VAE + llm embT + packed ctx_w transpose + loss partials ----
__global__ __launch_bounds__(64) void vae_kernel(
    const float* __restrict__ llms, const float* __restrict__ ctx_w,
    const float* __restrict__ fc1_w, const float* __restrict__ fc1_b,
    const float* __restrict__ fc21_w, const float* __restrict__ fc21_b,
    const float* __restrict__ fc22_w, const float* __restrict__ fc22_b,
    const float* __restrict__ fc3_w, const float* __restrict__ fc3_b,
    const float* __restrict__ fc4_w, const float* __restrict__ fc4_b,
    const float* __restrict__ eps,
    float* __restrict__ ctx_wP, float* __restrict__ embT,
    float* __restrict__ mse_row, float* __restrict__ kld_row)
{
    __shared__ __align__(16) float xs[D_IN];
    __shared__ __align__(16) float hs[HDIM];
    __shared__ __align__(16) float zs[HDIM];
    __shared__ __align__(16) float h2s[HDIM];
    const int r = blockIdx.x;
    const int j = threadIdx.x;

    // side job: pack-transpose ctx_w -> ctx_wP[(k4*64+j)*4+rr] = ctx_w[j*192+k4*4+rr]
    {
        int f = r * 64 + j;                       // [0, 16384); need [0, 12288)
        if (f < D_CTX * HDIM) {
            int p = f >> 2, rr = f & 3;
            int jc = p & 63, k4 = p >> 6;
            ctx_wP[f] = ctx_w[jc * D_CTX + k4 * 4 + rr];
        }
    }

    for (int k = j; k < D_IN; k += 64) xs[k] = llms[r * D_IN + k];
    __syncthreads();

    float acc = fc1_b[j];
    {
        const float4* wr = (const float4*)(fc1_w + (size_t)j * D_IN);
        const float4* xr = (const float4*)xs;
        #pragma unroll 8
        for (int k4 = 0; k4 < D_IN / 4; ++k4) { fma4(acc, wr[k4], xr[k4]); }
    }
    float h = fmaxf(acc, 0.0f);
    hs[j] = h;
    __syncthreads();

    float mu = fc21_b[j], lv = fc22_b[j];
    {
        const float4* w1 = (const float4*)(fc21_w + (size_t)j * HDIM);
        const float4* w2 = (const float4*)(fc22_w + (size_t)j * HDIM);
        const float4* hr = (const float4*)hs;
        #pragma unroll
        for (int k4 = 0; k4 < HDIM / 4; ++k4) {
            float4 hh = hr[k4];
            fma4(mu, w1[k4], hh);
            fma4(lv, w2[k4], hh);
        }
    }
    float stdv = expf(0.5f * lv) * 0.1f;
    float z = fmaf(eps[r * HDIM + j], stdv, mu);

    float elv = expf(lv);
    float kt = (1.0f - (-4.60517018598809136f)) + lv - (mu * mu + elv) / 0.01f;
    float ks = kt;
    #pragma unroll
    for (int o = 32; o; o >>= 1) ks += __shfl_xor(ks, o);

    float zsq = z * z;
    #pragma unroll
    for (int o = 32; o; o >>= 1) zsq += __shfl_xor(zsq, o);
    float nrm = fmaxf(sqrtf(zsq), 1e-12f);
    embT[j * N_L + r] = z / nrm;                 // transposed store (one-time scatter)
    zs[j] = z;
    __syncthreads();

    float a3 = fc3_b[j];
    {
        const float4* w3 = (const float4*)(fc3_w + (size_t)j * HDIM);
        const float4* zr = (const float4*)zs;
        #pragma unroll
        for (int k4 = 0; k4 < HDIM / 4; ++k4) { fma4(a3, w3[k4], zr[k4]); }
    }
    float h2 = fmaxf(a3, 0.0f);
    h2s[j] = h2;
    __syncthreads();

    float ms = 0.0f;
    const float4* h2r = (const float4*)h2s;
    #pragma unroll
    for (int m = 0; m < 6; ++m) {
        int o = j + 64 * m;
        float a4 = fc4_b[o];
        const float4* w4 = (const float4*)(fc4_w + (size_t)o * HDIM);
        #pragma unroll
        for (int k4 = 0; k4 < HDIM / 4; ++k4) { fma4(a4, w4[k4], h2r[k4]); }
        float d = a4 - xs[o];
        ms = fmaf(d, d, ms);
    }
    #pragma unroll
    for (int o = 32; o; o >>= 1) ms += __shfl_xor(ms, o);
    if (j == 0) { mse_row[r] = ms; kld_row[r] = ks; }
}

// ---------------- Kernel 2: FUSED routing ------------------------------------------------
// Identical arithmetic to the round-2 (103 us) kernel; structural change only: 64-thread
// (1-wave) blocks instead of 256-thread blocks. Waves never interacted (no barrier,
// per-wave LDS strips), so 1-wave blocks are semantics-preserving. LDS/block drops
// 24.6 KB -> 6 KB: 26 blocks/CU by LDS, 7 waves/SIMD by VGPR(<=73) -> wave-granular
// scheduling with no 6-then-2 block-round tail.
__global__ __launch_bounds__(64, 7) void route_kernel(
    const float* __restrict__ contexts, const float* __restrict__ ctx_wP, const float* __restrict__ ctx_b,
    const float* __restrict__ embT, const int* __restrict__ agent_num, const float* __restrict__ rand_u,
    const float* __restrict__ mse_row, const float* __restrict__ kld_row,
    float* __restrict__ out_sel, float* __restrict__ out_lp, float* __restrict__ out_loss)
{
    __shared__ __align__(16) float lds[1536];            // x-tile, e-strip overlays: 6 KB

    const int lane = threadIdx.x;                        // 0..63, one wave per block
    const int l0 = lane << 2;

    const int g = blockIdx.x;                            // wave id [0, 8192)
    const int q0 = __builtin_amdgcn_readfirstlane(g << 3);
    float* myl = lds;

    // ---- stage 8 context rows (6 KB contiguous, fully coalesced vector loads) ----
    {
        float4* xls = (float4*)myl;
        const float4* cbase = (const float4*)contexts + (size_t)q0 * (D_CTX / 4);
        #pragma unroll
        for (int it = 0; it < 6; ++it) {
            int f = lane + it * 64;                      // [0, 384)
            xls[f] = cbase[f];
        }
    }

    // ---- fold in vae_loss finalize (wave 0 only) ----
    if (g == 0) {
        int rr = lane * 4;
        float ms = mse_row[rr] + mse_row[rr + 1] + mse_row[rr + 2] + mse_row[rr + 3];
        float ks = kld_row[rr] + kld_row[rr + 1] + kld_row[rr + 2] + kld_row[rr + 3];
        #pragma unroll
        for (int o = 32; o; o >>= 1) { ms += __shfl_xor(ms, o); ks += __shfl_xor(ks, o); }
        if (lane == 0) out_loss[0] = ms / 98304.0f - 0.5f * (ks / 16384.0f);
    }

    // ---- agent counts: wave-uniform index -> scalar loads ----
    int Aq[8];
    #pragma unroll
    for (int q = 0; q < 8; ++q) Aq[q] = agent_num[q0 + q];

    // ---- phase 1: e_j (lane j) for 8 queries; w coalesced b128, x uniform LDS broadcast,
    //      packed fp32 FMAs (even/odd k split) ----
    const float bj = ctx_b[lane];
    v2f acc[8];
    #pragma unroll
    for (int q = 0; q < 8; ++q) acc[q] = mk2(bj, 0.0f);
    {
        const float4* wp = (const float4*)ctx_wP;
        const float4* xls = (const float4*)myl;
        #pragma unroll 2
        for (int k4 = 0; k4 < D_CTX / 4; ++k4) {
            float4 w = wp[k4 * HDIM + lane];             // lane-coalesced 1 KB load
            v2f w01 = mk2(w.x, w.y), w23 = mk2(w.z, w.w);
            #pragma unroll
            for (int q = 0; q < 8; ++q) {
                float4 xv = xls[q * 48 + k4];            // uniform broadcast ds_read_b128
                acc[q] = __builtin_elementwise_fma(w01, mk2(xv.x, xv.y), acc[q]);
                acc[q] = __builtin_elementwise_fma(w23, mk2(xv.z, xv.w), acc[q]);
            }
        }
    }
    float e[8];
    #pragma unroll
    for (int q = 0; q < 8; ++q) e[q] = acc[q].x + acc[q].y;
    #pragma unroll
    for (int q = 0; q < 8; ++q) {
        float s = bc63(wave_iscan(e[q] * e[q]));         // wave sum via DPP -> SGPR
        e[q] *= 1.0f / fmaxf(sqrtf(s), 1e-12f);
        myl[q * HDIM + lane] = e[q];                     // e-strip overlays dead x region
    }

    // ---- phase 2: logits, lane's 4 llms x 8 queries; packed fp32, op_sel e-broadcast ----
    v2f Pa[8], Pb[8];                                    // (l0,l0+1) and (l0+2,l0+3)
    #pragma unroll
    for (int q = 0; q < 8; ++q) { Pa[q] = mk2(0.0f, 0.0f); Pb[q] = mk2(0.0f, 0.0f); }

    #pragma unroll 2
    for (int j4 = 0; j4 < HDIM / 4; ++j4) {
        float4 M0 = *(const float4*)(embT + (size_t)(j4 * 4 + 0) * N_L + l0);  // coalesced
        float4 M1 = *(const float4*)(embT + (size_t)(j4 * 4 + 1) * N_L + l0);
        float4 M2 = *(const float4*)(embT + (size_t)(j4 * 4 + 2) * N_L + l0);
        float4 M3 = *(const float4*)(embT + (size_t)(j4 * 4 + 3) * N_L + l0);
        v2f m0a = mk2(M0.x, M0.y), m0b = mk2(M0.z, M0.w);
        v2f m1a = mk2(M1.x, M1.y), m1b = mk2(M1.z, M1.w);
        v2f m2a = mk2(M2.x, M2.y), m2b = mk2(M2.z, M2.w);
        v2f m3a = mk2(M3.x, M3.y), m3b = mk2(M3.z, M3.w);
        #pragma unroll
        for (int q = 0; q < 8; ++q) {
            float4 ev = *(const float4*)(myl + q * HDIM + j4 * 4);   // uniform LDS broadcast
            v2f e01 = mk2(ev.x, ev.y), e23 = mk2(ev.z, ev.w);
            // per-component order identical to prior rounds: M0*ev.x, M1*ev.y, M2*ev.z, M3*ev.w
            pk_fma_lo(Pa[q], m0a, e01);
            pk_fma_hi(Pa[q], m1a, e01);
            pk_fma_lo(Pa[q], m2a, e23);
            pk_fma_hi(Pa[q], m3a, e23);
            pk_fma_lo(Pb[q], m0b, e01);
            pk_fma_hi(Pb[q], m1b, e01);
            pk_fma_lo(Pb[q], m2b, e23);
            pk_fma_hi(Pb[q], m3b, e23);
        }
    }

    float4 P[8];
    #pragma unroll
    for (int k = 0; k < 8; ++k) P[k] = make_float4(Pa[k].x, Pa[k].y, Pb[k].x, Pb[k].y);

    // ---- softmax (DPP max/sum; same per-query op order) ----
    #pragma unroll
    for (int k = 0; k < 8; ++k) {
        float m = fmaxf(fmaxf(P[k].x, P[k].y), fmaxf(P[k].z, P[k].w));
        m = bc63(wave_max_l63(m));                       // exact wave max
        P[k].x = expf(P[k].x - m); P[k].y = expf(P[k].y - m);
        P[k].z = expf(P[k].z - m); P[k].w = expf(P[k].w - m);
        float s = bc63(wave_iscan(P[k].x + P[k].y + P[k].z + P[k].w));
        float inv = 1.0f / s;
        P[k].x *= inv; P[k].y *= inv; P[k].z *= inv; P[k].w *= inv;
    }

    // ---- inclusive cumsum via DPP scan ----
    float c0[8], c1[8], c2[8], c3[8];
    #pragma unroll
    for (int k = 0; k < 8; ++k) {
        c0[k] = P[k].x; c1[k] = c0[k] + P[k].y; c2[k] = c1[k] + P[k].z;
        float p3 = c2[k] + P[k].w;
        float t = wave_iscan(p3);
        float base = t - p3;
        c0[k] += base; c1[k] += base; c2[k] += base; c3[k] = p3 + base;
    }

    // ---- sampling: ballot+popcount; u via wave-uniform scalar load ----
    unsigned nib[8] = {0, 0, 0, 0, 0, 0, 0, 0};
    #pragma unroll
    for (int i = 0; i < MAXA; ++i) {
        #pragma unroll
        for (int k = 0; k < 8; ++k) {
            if (i < Aq[k]) {                       // wave-uniform scalar branch
                float u = rand_u[(size_t)i * N_Q + q0 + k];   // uniform -> s_load
                unsigned long long b0 = __ballot(c0[k] <= u);
                unsigned long long b1 = __ballot(c1[k] <= u);
                unsigned long long b2 = __ballot(c2[k] <= u);
                unsigned long long b3 = __ballot(c3[k] <= u);
                int loc = __popcll(b0) + __popcll(b1) + __popcll(b2) + __popcll(b3);
                int sel = (loc >= N_L) ? 0 : loc;  // numpy argmax(all-False) == 0
                unsigned d = (unsigned)(sel - l0);
                if (d < 4u) nib[k] += 1u << (4 * d);
            }
        }
    }

    // ---- row stores + log-prob terms (same per-query arithmetic/order) ----
    float term[8];
    #pragma unroll
    for (int k = 0; k < 8; ++k) {
        int n0 = nib[k] & 15, n1 = (nib[k] >> 4) & 15, n2 = (nib[k] >> 8) & 15, n3 = (nib[k] >> 12) & 15;
        float4 rowv = make_float4((float)n0, (float)n1, (float)n2, (float)n3);
        *(((float4*)(out_sel + (size_t)(q0 + k) * N_L)) + lane) = rowv;
        float tm = 0.0f;
        if (n0) tm += (float)n0 * logf(P[k].x) - lgfact(n0);
        if (n1) tm += (float)n1 * logf(P[k].y) - lgfact(n1);
        if (n2) tm += (float)n2 * logf(P[k].z) - lgfact(n2);
        if (n3) tm += (float)n3 * logf(P[k].w) - lgfact(n3);
        term[k] = tm;
    }
    float st[8];
    #pragma unroll
    for (int k = 0; k < 8; ++k) st[k] = bc63(wave_iscan(term[k]));

    if (lane < 8) {
        float rr = st[0];
        int Aa = Aq[0];
        #pragma unroll
        for (int k = 1; k < 8; ++k) {
            if (lane == k) { rr = st[k]; Aa = Aq[k]; }
        }
        out_lp[q0 + lane] = lgfact(Aa) + rr;
    }
}

extern "C" void kernel_launch(void* const* d_in, const int* in_sizes, int n_in,
                              void* d_out, int out_size, void* d_ws, size_t ws_size,
                              hipStream_t stream) {
    const float* llms      = (const float*)d_in[0];
    const float* contexts  = (const float*)d_in[1];
    const int*   agent_i   = (const int*)  d_in[2];
    // d_in[3] agent_num_float unused (int version + table)
    const float* fc1_w  = (const float*)d_in[4];  const float* fc1_b  = (const float*)d_in[5];
    const float* fc21_w = (const float*)d_in[6];  const float* fc21_b = (const float*)d_in[7];
    const float* fc22_w = (const float*)d_in[8];  const float* fc22_b = (const float*)d_in[9];
    const float* fc3_w  = (const float*)d_in[10]; const float* fc3_b  = (const float*)d_in[11];
    const float* fc4_w  = (const float*)d_in[12]; const float* fc4_b  = (const float*)d_in[13];
    const float* ctx_w  = (const float*)d_in[14]; const float* ctx_b  = (const float*)d_in[15];
    const float* noise  = (const float*)d_in[16]; const float* rand_u = (const float*)d_in[17];

    float* out      = (float*)d_out;
    float* out_sel  = out;                          // [65536][256]
    float* out_lp   = out + (size_t)N_Q * N_L;      // [65536]
    float* out_loss = out_lp + N_Q;                 // [1]

    float* ctx_wP   = (float*)d_ws;                 // [48][64] float4 (12288 floats)
    float* embT     = ctx_wP + D_CTX * HDIM;        // [64][256]
    float* mse_row  = embT + HDIM * N_L;            // [256]
    float* kld_row  = mse_row + N_L;                // [256]

    vae_kernel<<<N_L, 64, 0, stream>>>(llms, ctx_w, fc1_w, fc1_b, fc21_w, fc21_b, fc22_w, fc22_b,
                                       fc3_w, fc3_b, fc4_w, fc4_b, noise,
                                       ctx_wP, embT, mse_row, kld_row);
    route_kernel<<<8192, 64, 0, stream>>>(contexts, ctx_wP, ctx_b, embT, agent_i, rand_u,
                                          mse_row, kld_row, out_sel, out_lp, out_loss);
}

// Round 5
// 223.222 us; speedup vs baseline: 1.1444x; 1.1444x over previous
//
#include <hip/hip_runtime.h>

#define N_L 256
#define N_Q 65536
#define D_IN 384
#define D_CTX 192
#define HDIM 64
#define MAXA 6

typedef float v2f __attribute__((ext_vector_type(2)));

__device__ __forceinline__ v2f mk2(float a, float b) { v2f r; r.x = a; r.y = b; return r; }

__device__ __forceinline__ void fma4(float& acc, const float4& w, const float4& v) {
    acc = fmaf(w.x, v.x, acc);
    acc = fmaf(w.y, v.y, acc);
    acc = fmaf(w.z, v.z, acc);
    acc = fmaf(w.w, v.w, acc);
}

__device__ __forceinline__ float lgfact(int n) {
    // log(n!) for n in 0..6  (== gammaln(n+1))
    return (n <= 1) ? 0.0f :
           (n == 2) ? 0.6931471805599453f :
           (n == 3) ? 1.7917594692280550f :
           (n == 4) ? 3.1780538303479458f :
           (n == 5) ? 4.7874917427820460f :
                      6.5792512120101010f;
}

// ---------------- DPP wave reduction helpers (VALU pipe, no LDS traffic) ----------------
template<int CTRL, int RM, bool BC>
__device__ __forceinline__ float dppz(float x) {   // old = 0 (masked/invalid lanes contribute 0)
    return __int_as_float(__builtin_amdgcn_update_dpp(0, __float_as_int(x), CTRL, RM, 0xF, BC));
}
template<int CTRL, int RM>
__device__ __forceinline__ float dpps(float x) {   // old = x (identity for max)
    int xi = __float_as_int(x);
    return __int_as_float(__builtin_amdgcn_update_dpp(xi, xi, CTRL, RM, 0xF, false));
}
// inclusive prefix-sum across 64 lanes; lane 63 ends with the wave total
__device__ __forceinline__ float wave_iscan(float t) {
    t += dppz<0x111, 0xF, true>(t);    // row_shr:1, 0-fill
    t += dppz<0x112, 0xF, true>(t);    // row_shr:2
    t += dppz<0x114, 0xF, true>(t);    // row_shr:4
    t += dppz<0x118, 0xF, true>(t);    // row_shr:8
    t += dppz<0x142, 0xA, false>(t);   // row_bcast:15 -> rows 1,3
    t += dppz<0x143, 0xC, false>(t);   // row_bcast:31 -> rows 2,3
    return t;
}
// wave max; lane 63 ends with the full 64-lane max (exact, max is associative)
__device__ __forceinline__ float wave_max_l63(float m) {
    m = fmaxf(m, dpps<0x111, 0xF>(m));
    m = fmaxf(m, dpps<0x112, 0xF>(m));
    m = fmaxf(m, dpps<0x114, 0xF>(m));
    m = fmaxf(m, dpps<0x118, 0xF>(m));
    m = fmaxf(m, dpps<0x142, 0xA>(m));
    m = fmaxf(m, dpps<0x143, 0xC>(m));
    return m;
}
__device__ __forceinline__ float bc63(float x) {   // broadcast lane 63 via SGPR
    return __int_as_float(__builtin_amdgcn_readlane(__float_as_int(x), 63));
}

// ---------------- packed fp32 FMA with op_sel broadcast of one half of src1 ----------------
// d.lo += a.lo * b.lo ; d.hi += a.hi * b.lo
__device__ __forceinline__ void pk_fma_lo(v2f& d, v2f a, v2f b) {
    asm("v_pk_fma_f32 %0, %1, %2, %0 op_sel:[0,0,0] op_sel_hi:[1,0,1]"
        : "+v"(d) : "v"(a), "v"(b));
}
// d.lo += a.lo * b.hi ; d.hi += a.hi * b.hi
__device__ __forceinline__ void pk_fma_hi(v2f& d, v2f a, v2f b) {
    asm("v_pk_fma_f32 %0, %1, %2, %0 op_sel:[0,1,0] op_sel_hi:[1,1,1]"
        : "+v"(d) : "v"(a), "v"(b));
}

// ---------------- Kernel 1: VAE + llm embT + packed ctx_w transpose + loss partials ----
__global__ __launch_bounds__(64) void vae_kernel(
    const float* __restrict__ llms, const float* __restrict__ ctx_w,
    const float* __restrict__ fc1_w, const float* __restrict__ fc1_b,
    const float* __restrict__ fc21_w, const float* __restrict__ fc21_b,
    const float* __restrict__ fc22_w, const float* __restrict__ fc22_b,
    const float* __restrict__ fc3_w, const float* __restrict__ fc3_b,
    const float* __restrict__ fc4_w, const float* __restrict__ fc4_b,
    const float* __restrict__ eps,
    float* __restrict__ ctx_wP, float* __restrict__ embT,
    float* __restrict__ mse_row, float* __restrict__ kld_row)
{
    __shared__ __align__(16) float xs[D_IN];
    __shared__ __align__(16) float hs[HDIM];
    __shared__ __align__(16) float zs[HDIM];
    __shared__ __align__(16) float h2s[HDIM];
    const int r = blockIdx.x;
    const int j = threadIdx.x;

    // side job: pack-transpose ctx_w -> ctx_wP[(k4*64+j)*4+rr] = ctx_w[j*192+k4*4+rr]
    {
        int f = r * 64 + j;                       // [0, 16384); need [0, 12288)
        if (f < D_CTX * HDIM) {
            int p = f >> 2, rr = f & 3;
            int jc = p & 63, k4 = p >> 6;
            ctx_wP[f] = ctx_w[jc * D_CTX + k4 * 4 + rr];
        }
    }

    for (int k = j; k < D_IN; k += 64) xs[k] = llms[r * D_IN + k];
    __syncthreads();

    float acc = fc1_b[j];
    {
        const float4* wr = (const float4*)(fc1_w + (size_t)j * D_IN);
        const float4* xr = (const float4*)xs;
        #pragma unroll 8
        for (int k4 = 0; k4 < D_IN / 4; ++k4) { fma4(acc, wr[k4], xr[k4]); }
    }
    float h = fmaxf(acc, 0.0f);
    hs[j] = h;
    __syncthreads();

    float mu = fc21_b[j], lv = fc22_b[j];
    {
        const float4* w1 = (const float4*)(fc21_w + (size_t)j * HDIM);
        const float4* w2 = (const float4*)(fc22_w + (size_t)j * HDIM);
        const float4* hr = (const float4*)hs;
        #pragma unroll
        for (int k4 = 0; k4 < HDIM / 4; ++k4) {
            float4 hh = hr[k4];
            fma4(mu, w1[k4], hh);
            fma4(lv, w2[k4], hh);
        }
    }
    float stdv = expf(0.5f * lv) * 0.1f;
    float z = fmaf(eps[r * HDIM + j], stdv, mu);

    float elv = expf(lv);
    float kt = (1.0f - (-4.60517018598809136f)) + lv - (mu * mu + elv) / 0.01f;
    float ks = kt;
    #pragma unroll
    for (int o = 32; o; o >>= 1) ks += __shfl_xor(ks, o);

    float zsq = z * z;
    #pragma unroll
    for (int o = 32; o; o >>= 1) zsq += __shfl_xor(zsq, o);
    float nrm = fmaxf(sqrtf(zsq), 1e-12f);
    embT[j * N_L + r] = z / nrm;                 // transposed store (one-time scatter)
    zs[j] = z;
    __syncthreads();

    float a3 = fc3_b[j];
    {
        const float4* w3 = (const float4*)(fc3_w + (size_t)j * HDIM);
        const float4* zr = (const float4*)zs;
        #pragma unroll
        for (int k4 = 0; k4 < HDIM / 4; ++k4) { fma4(a3, w3[k4], zr[k4]); }
    }
    float h2 = fmaxf(a3, 0.0f);
    h2s[j] = h2;
    __syncthreads();

    float ms = 0.0f;
    const float4* h2r = (const float4*)h2s;
    #pragma unroll
    for (int m = 0; m < 6; ++m) {
        int o = j + 64 * m;
        float a4 = fc4_b[o];
        const float4* w4 = (const float4*)(fc4_w + (size_t)o * HDIM);
        #pragma unroll
        for (int k4 = 0; k4 < HDIM / 4; ++k4) { fma4(a4, w4[k4], h2r[k4]); }
        float d = a4 - xs[o];
        ms = fmaf(d, d, ms);
    }
    #pragma unroll
    for (int o = 32; o; o >>= 1) ms += __shfl_xor(ms, o);
    if (j == 0) { mse_row[r] = ms; kld_row[r] = ks; }
}

// ---------------- Kernel 2: FUSED routing ------------------------------------------------
// Round-2 (103 us) structure exactly: 256-thread blocks, per-wave 6 KB x-tile staged via
// coalesced float4, pk_fma GEMV phases, DPP reductions. Register-pressure fix only:
// softmax+cumsum fused per-query so the 32 P registers die as the 32 c registers are born
// (sampling reads c only; log-prob p reconstructed from cumsum deltas — validated in the
// round-3 pass). Goal: VGPR <= 64 (the 8->4 waves/SIMD cliff) WITHOUT any forced
// waves-per-EU bound (those spilled in rounds 3/4). Sampling ballots bit-identical to
// round 2.
__global__ __launch_bounds__(256) void route_kernel(
    const float* __restrict__ contexts, const float* __restrict__ ctx_wP, const float* __restrict__ ctx_b,
    const float* __restrict__ embT, const int* __restrict__ agent_num, const float* __restrict__ rand_u,
    const float* __restrict__ mse_row, const float* __restrict__ kld_row,
    float* __restrict__ out_sel, float* __restrict__ out_lp, float* __restrict__ out_loss)
{
    __shared__ __align__(16) float lds[4][1536];         // x-tile, e-strip overlays: 24 KB

    const int tid = threadIdx.x;
    const int lane = tid & 63;
    const int widx = tid >> 6;
    const int l0 = lane << 2;

    const int g = blockIdx.x * 4 + widx;                 // wave id [0, 8192)
    const int q0 = __builtin_amdgcn_readfirstlane(g << 3);
    float* myl = lds[widx];

    // ---- stage 8 context rows (6 KB contiguous, fully coalesced vector loads) ----
    {
        float4* xls = (float4*)myl;
        const float4* cbase = (const float4*)contexts + (size_t)q0 * (D_CTX / 4);
        #pragma unroll
        for (int it = 0; it < 6; ++it) {
            int f = lane + it * 64;                      // [0, 384)
            xls[f] = cbase[f];
        }
    }

    // ---- fold in vae_loss finalize (wave 0 only) ----
    if (g == 0) {
        int rr = lane * 4;
        float ms = mse_row[rr] + mse_row[rr + 1] + mse_row[rr + 2] + mse_row[rr + 3];
        float ks = kld_row[rr] + kld_row[rr + 1] + kld_row[rr + 2] + kld_row[rr + 3];
        #pragma unroll
        for (int o = 32; o; o >>= 1) { ms += __shfl_xor(ms, o); ks += __shfl_xor(ks, o); }
        if (lane == 0) out_loss[0] = ms / 98304.0f - 0.5f * (ks / 16384.0f);
    }

    // ---- agent counts: wave-uniform index -> scalar loads ----
    int Aq[8];
    #pragma unroll
    for (int q = 0; q < 8; ++q) Aq[q] = agent_num[q0 + q];

    // ---- phase 1: e_j (lane j) for 8 queries; w coalesced b128, x uniform LDS broadcast,
    //      packed fp32 FMAs (even/odd k split) ----
    const float bj = ctx_b[lane];
    v2f acc[8];
    #pragma unroll
    for (int q = 0; q < 8; ++q) acc[q] = mk2(bj, 0.0f);
    {
        const float4* wp = (const float4*)ctx_wP;
        const float4* xls = (const float4*)myl;
        #pragma unroll 2
        for (int k4 = 0; k4 < D_CTX / 4; ++k4) {
            float4 w = wp[k4 * HDIM + lane];             // lane-coalesced 1 KB load
            v2f w01 = mk2(w.x, w.y), w23 = mk2(w.z, w.w);
            #pragma unroll
            for (int q = 0; q < 8; ++q) {
                float4 xv = xls[q * 48 + k4];            // uniform broadcast ds_read_b128
                acc[q] = __builtin_elementwise_fma(w01, mk2(xv.x, xv.y), acc[q]);
                acc[q] = __builtin_elementwise_fma(w23, mk2(xv.z, xv.w), acc[q]);
            }
        }
    }
    float e[8];
    #pragma unroll
    for (int q = 0; q < 8; ++q) e[q] = acc[q].x + acc[q].y;
    #pragma unroll
    for (int q = 0; q < 8; ++q) {
        float s = bc63(wave_iscan(e[q] * e[q]));         // wave sum via DPP -> SGPR
        e[q] *= 1.0f / fmaxf(sqrtf(s), 1e-12f);
        myl[q * HDIM + lane] = e[q];                     // e-strip overlays dead x region
    }

    // ---- phase 2: logits, lane's 4 llms x 8 queries; packed fp32, op_sel e-broadcast ----
    v2f Pa[8], Pb[8];                                    // (l0,l0+1) and (l0+2,l0+3)
    #pragma unroll
    for (int q = 0; q < 8; ++q) { Pa[q] = mk2(0.0f, 0.0f); Pb[q] = mk2(0.0f, 0.0f); }

    #pragma unroll 2
    for (int j4 = 0; j4 < HDIM / 4; ++j4) {
        float4 M0 = *(const float4*)(embT + (size_t)(j4 * 4 + 0) * N_L + l0);  // coalesced
        float4 M1 = *(const float4*)(embT + (size_t)(j4 * 4 + 1) * N_L + l0);
        float4 M2 = *(const float4*)(embT + (size_t)(j4 * 4 + 2) * N_L + l0);
        float4 M3 = *(const float4*)(embT + (size_t)(j4 * 4 + 3) * N_L + l0);
        v2f m0a = mk2(M0.x, M0.y), m0b = mk2(M0.z, M0.w);
        v2f m1a = mk2(M1.x, M1.y), m1b = mk2(M1.z, M1.w);
        v2f m2a = mk2(M2.x, M2.y), m2b = mk2(M2.z, M2.w);
        v2f m3a = mk2(M3.x, M3.y), m3b = mk2(M3.z, M3.w);
        #pragma unroll
        for (int q = 0; q < 8; ++q) {
            float4 ev = *(const float4*)(myl + q * HDIM + j4 * 4);   // uniform LDS broadcast
            v2f e01 = mk2(ev.x, ev.y), e23 = mk2(ev.z, ev.w);
            // per-component order identical to prior rounds: M0*ev.x, M1*ev.y, M2*ev.z, M3*ev.w
            pk_fma_lo(Pa[q], m0a, e01);
            pk_fma_hi(Pa[q], m1a, e01);
            pk_fma_lo(Pa[q], m2a, e23);
            pk_fma_hi(Pa[q], m3a, e23);
            pk_fma_lo(Pb[q], m0b, e01);
            pk_fma_hi(Pb[q], m1b, e01);
            pk_fma_lo(Pb[q], m2b, e23);
            pk_fma_hi(Pb[q], m3b, e23);
        }
    }

    // ---- softmax + inclusive cumsum fused per query (DPP; identical per-component op
    //      order to round 2). Pa/Pb die here as c0..c3 are born -> VGPR peak drops ~32. ----
    float c0[8], c1[8], c2[8], c3[8];
    #pragma unroll
    for (int k = 0; k < 8; ++k) {
        float px = Pa[k].x, py = Pa[k].y, pz = Pb[k].x, pw = Pb[k].y;
        float m = fmaxf(fmaxf(px, py), fmaxf(pz, pw));
        m = bc63(wave_max_l63(m));                       // exact wave max
        px = expf(px - m); py = expf(py - m);
        pz = expf(pz - m); pw = expf(pw - m);
        float s = bc63(wave_iscan(px + py + pz + pw));
        float inv = 1.0f / s;
        px *= inv; py *= inv; pz *= inv; pw *= inv;
        c0[k] = px; c1[k] = c0[k] + py; c2[k] = c1[k] + pz;
        float p3 = c2[k] + pw;
        float t = wave_iscan(p3);
        float base = t - p3;
        c0[k] += base; c1[k] += base; c2[k] += base; c3[k] = p3 + base;
    }

    // ---- sampling: ballot+popcount on cumsum only; u via wave-uniform scalar load ----
    unsigned nib[8] = {0, 0, 0, 0, 0, 0, 0, 0};
    #pragma unroll
    for (int i = 0; i < MAXA; ++i) {
        #pragma unroll
        for (int k = 0; k < 8; ++k) {
            if (i < Aq[k]) {                       // wave-uniform scalar branch
                float u = rand_u[(size_t)i * N_Q + q0 + k];   // uniform -> s_load
                unsigned long long b0 = __ballot(c0[k] <= u);
                unsigned long long b1 = __ballot(c1[k] <= u);
                unsigned long long b2 = __ballot(c2[k] <= u);
                unsigned long long b3 = __ballot(c3[k] <= u);
                int loc = __popcll(b0) + __popcll(b1) + __popcll(b2) + __popcll(b3);
                int sel = (loc >= N_L) ? 0 : loc;  // numpy argmax(all-False) == 0
                unsigned d = (unsigned)(sel - l0);
                if (d < 4u) nib[k] += 1u << (4 * d);
            }
        }
    }

    // ---- row stores + log-prob terms; p reconstructed from cumsum deltas (validated
    //      numerically by the round-3 pass) ----
    float term[8];
    #pragma unroll
    for (int k = 0; k < 8; ++k) {
        int n0 = nib[k] & 15, n1 = (nib[k] >> 4) & 15, n2 = (nib[k] >> 8) & 15, n3 = (nib[k] >> 12) & 15;
        float4 rowv = make_float4((float)n0, (float)n1, (float)n2, (float)n3);
        *(((float4*)(out_sel + (size_t)(q0 + k) * N_L)) + lane) = rowv;
        float base = __shfl_up(c3[k], 1);
        base = (lane == 0) ? 0.0f : base;
        float px = c0[k] - base, py = c1[k] - c0[k], pz = c2[k] - c1[k], pw = c3[k] - c2[k];
        float tm = 0.0f;
        if (n0) tm += (float)n0 * logf(px) - lgfact(n0);
        if (n1) tm += (float)n1 * logf(py) - lgfact(n1);
        if (n2) tm += (float)n2 * logf(pz) - lgfact(n2);
        if (n3) tm += (float)n3 * logf(pw) - lgfact(n3);
        term[k] = tm;
    }
    float st[8];
    #pragma unroll
    for (int k = 0; k < 8; ++k) st[k] = bc63(wave_iscan(term[k]));

    if (lane < 8) {
        float rr = st[0];
        int Aa = Aq[0];
        #pragma unroll
        for (int k = 1; k < 8; ++k) {
            if (lane == k) { rr = st[k]; Aa = Aq[k]; }
        }
        out_lp[q0 + lane] = lgfact(Aa) + rr;
    }
}

extern "C" void kernel_launch(void* const* d_in, const int* in_sizes, int n_in,
                              void* d_out, int out_size, void* d_ws, size_t ws_size,
                              hipStream_t stream) {
    const float* llms      = (const float*)d_in[0];
    const float* contexts  = (const float*)d_in[1];
    const int*   agent_i   = (const int*)  d_in[2];
    // d_in[3] agent_num_float unused (int version + table)
    const float* fc1_w  = (const float*)d_in[4];  const float* fc1_b  = (const float*)d_in[5];
    const float* fc21_w = (const float*)d_in[6];  const float* fc21_b = (const float*)d_in[7];
    const float* fc22_w = (const float*)d_in[8];  const float* fc22_b = (const float*)d_in[9];
    const float* fc3_w  = (const float*)d_in[10]; const float* fc3_b  = (const float*)d_in[11];
    const float* fc4_w  = (const float*)d_in[12]; const float* fc4_b  = (const float*)d_in[13];
    const float* ctx_w  = (const float*)d_in[14]; const float* ctx_b  = (const float*)d_in[15];
    const float* noise  = (const float*)d_in[16]; const float* rand_u = (const float*)d_in[17];

    float* out      = (float*)d_out;
    float* out_sel  = out;                          // [65536][256]
    float* out_lp   = out + (size_t)N_Q * N_L;      // [65536]
    float* out_loss = out_lp + N_Q;                 // [1]

    float* ctx_wP   = (float*)d_ws;                 // [48][64] float4 (12288 floats)
    float* embT     = ctx_wP + D_CTX * HDIM;        // [64][256]
    float* mse_row  = embT + HDIM * N_L;            // [256]
    float* kld_row  = mse_row + N_L;                // [256]

    vae_kernel<<<N_L, 64, 0, stream>>>(llms, ctx_w, fc1_w, fc1_b, fc21_w, fc21_b, fc22_w, fc22_b,
                                       fc3_w, fc3_b, fc4_w, fc4_b, noise,
                                       ctx_wP, embT, mse_row, kld_row);
    route_kernel<<<2048, 256, 0, stream>>>(contexts, ctx_wP, ctx_b, embT, agent_i, rand_u,
                                           mse_row, kld_row, out_sel, out_lp, out_loss);
}

// Round 6
// 222.902 us; speedup vs baseline: 1.1460x; 1.0014x over previous
//
#include <hip/hip_runtime.h>

#define N_L 256
#define N_Q 65536
#define D_IN 384
#define D_CTX 192
#define HDIM 64
#define MAXA 6

typedef float v2f __attribute__((ext_vector_type(2)));

__device__ __forceinline__ v2f mk2(float a, float b) { v2f r; r.x = a; r.y = b; return r; }

__device__ __forceinline__ void fma4(float& acc, const float4& w, const float4& v) {
    acc = fmaf(w.x, v.x, acc);
    acc = fmaf(w.y, v.y, acc);
    acc = fmaf(w.z, v.z, acc);
    acc = fmaf(w.w, v.w, acc);
}

__device__ __forceinline__ float lgfact(int n) {
    // log(n!) for n in 0..6  (== gammaln(n+1))
    return (n <= 1) ? 0.0f :
           (n == 2) ? 0.6931471805599453f :
           (n == 3) ? 1.7917594692280550f :
           (n == 4) ? 3.1780538303479458f :
           (n == 5) ? 4.7874917427820460f :
                      6.5792512120101010f;
}

// ---------------- DPP wave reduction helpers (VALU pipe, no LDS traffic) ----------------
template<int CTRL, int RM, bool BC>
__device__ __forceinline__ float dppz(float x) {   // old = 0 (masked/invalid lanes contribute 0)
    return __int_as_float(__builtin_amdgcn_update_dpp(0, __float_as_int(x), CTRL, RM, 0xF, BC));
}
template<int CTRL, int RM>
__device__ __forceinline__ float dpps(float x) {   // old = x (identity for max)
    int xi = __float_as_int(x);
    return __int_as_float(__builtin_amdgcn_update_dpp(xi, xi, CTRL, RM, 0xF, false));
}
// inclusive prefix-sum across 64 lanes; lane 63 ends with the wave total
__device__ __forceinline__ float wave_iscan(float t) {
    t += dppz<0x111, 0xF, true>(t);    // row_shr:1, 0-fill
    t += dppz<0x112, 0xF, true>(t);    // row_shr:2
    t += dppz<0x114, 0xF, true>(t);    // row_shr:4
    t += dppz<0x118, 0xF, true>(t);    // row_shr:8
    t += dppz<0x142, 0xA, false>(t);   // row_bcast:15 -> rows 1,3
    t += dppz<0x143, 0xC, false>(t);   // row_bcast:31 -> rows 2,3
    return t;
}
// wave max; lane 63 ends with the full 64-lane max (exact, max is associative)
__device__ __forceinline__ float wave_max_l63(float m) {
    m = fmaxf(m, dpps<0x111, 0xF>(m));
    m = fmaxf(m, dpps<0x112, 0xF>(m));
    m = fmaxf(m, dpps<0x114, 0xF>(m));
    m = fmaxf(m, dpps<0x118, 0xF>(m));
    m = fmaxf(m, dpps<0x142, 0xA>(m));
    m = fmaxf(m, dpps<0x143, 0xC>(m));
    return m;
}
__device__ __forceinline__ float bc63(float x) {   // broadcast lane 63 via SGPR
    return __int_as_float(__builtin_amdgcn_readlane(__float_as_int(x), 63));
}

// ---------------- packed fp32 FMA with op_sel broadcast of one half of src1 ----------------
// d.lo += a.lo * b.lo ; d.hi += a.hi * b.lo
__device__ __forceinline__ void pk_fma_lo(v2f& d, v2f a, v2f b) {
    asm("v_pk_fma_f32 %0, %1, %2, %0 op_sel:[0,0,0] op_sel_hi:[1,0,1]"
        : "+v"(d) : "v"(a), "v"(b));
}
// d.lo += a.lo * b.hi ; d.hi += a.hi * b.hi
__device__ __forceinline__ void pk_fma_hi(v2f& d, v2f a, v2f b) {
    asm("v_pk_fma_f32 %0, %1, %2, %0 op_sel:[0,1,0] op_sel_hi:[1,1,1]"
        : "+v"(d) : "v"(a), "v"(b));
}

// ---------------- Kernel 1: VAE + llm embT + packed ctx_w transpose + loss partials ----
__global__ __launch_bounds__(64) void vae_kernel(
    const float* __restrict__ llms, const float* __restrict__ ctx_w,
    const float* __restrict__ fc1_w, const float* __restrict__ fc1_b,
    const float* __restrict__ fc21_w, const float* __restrict__ fc21_b,
    const float* __restrict__ fc22_w, const float* __restrict__ fc22_b,
    const float* __restrict__ fc3_w, const float* __restrict__ fc3_b,
    const float* __restrict__ fc4_w, const float* __restrict__ fc4_b,
    const float* __restrict__ eps,
    float* __restrict__ ctx_wP, float* __restrict__ embT,
    float* __restrict__ mse_row, float* __restrict__ kld_row)
{
    __shared__ __align__(16) float xs[D_IN];
    __shared__ __align__(16) float hs[HDIM];
    __shared__ __align__(16) float zs[HDIM];
    __shared__ __align__(16) float h2s[HDIM];
    const int r = blockIdx.x;
    const int j = threadIdx.x;

    // side job: pack-transpose ctx_w -> ctx_wP[(k4*64+j)*4+rr] = ctx_w[j*192+k4*4+rr]
    {
        int f = r * 64 + j;                       // [0, 16384); need [0, 12288)
        if (f < D_CTX * HDIM) {
            int p = f >> 2, rr = f & 3;
            int jc = p & 63, k4 = p >> 6;
            ctx_wP[f] = ctx_w[jc * D_CTX + k4 * 4 + rr];
        }
    }

    for (int k = j; k < D_IN; k += 64) xs[k] = llms[r * D_IN + k];
    __syncthreads();

    float acc = fc1_b[j];
    {
        const float4* wr = (const float4*)(fc1_w + (size_t)j * D_IN);
        const float4* xr = (const float4*)xs;
        #pragma unroll 8
        for (int k4 = 0; k4 < D_IN / 4; ++k4) { fma4(acc, wr[k4], xr[k4]); }
    }
    float h = fmaxf(acc, 0.0f);
    hs[j] = h;
    __syncthreads();

    float mu = fc21_b[j], lv = fc22_b[j];
    {
        const float4* w1 = (const float4*)(fc21_w + (size_t)j * HDIM);
        const float4* w2 = (const float4*)(fc22_w + (size_t)j * HDIM);
        const float4* hr = (const float4*)hs;
        #pragma unroll
        for (int k4 = 0; k4 < HDIM / 4; ++k4) {
            float4 hh = hr[k4];
            fma4(mu, w1[k4], hh);
            fma4(lv, w2[k4], hh);
        }
    }
    float stdv = expf(0.5f * lv) * 0.1f;
    float z = fmaf(eps[r * HDIM + j], stdv, mu);

    float elv = expf(lv);
    float kt = (1.0f - (-4.60517018598809136f)) + lv - (mu * mu + elv) / 0.01f;
    float ks = kt;
    #pragma unroll
    for (int o = 32; o; o >>= 1) ks += __shfl_xor(ks, o);

    float zsq = z * z;
    #pragma unroll
    for (int o = 32; o; o >>= 1) zsq += __shfl_xor(zsq, o);
    float nrm = fmaxf(sqrtf(zsq), 1e-12f);
    embT[j * N_L + r] = z / nrm;                 // transposed store (one-time scatter)
    zs[j] = z;
    __syncthreads();

    float a3 = fc3_b[j];
    {
        const float4* w3 = (const float4*)(fc3_w + (size_t)j * HDIM);
        const float4* zr = (const float4*)zs;
        #pragma unroll
        for (int k4 = 0; k4 < HDIM / 4; ++k4) { fma4(a3, w3[k4], zr[k4]); }
    }
    float h2 = fmaxf(a3, 0.0f);
    h2s[j] = h2;
    __syncthreads();

    float ms = 0.0f;
    const float4* h2r = (const float4*)h2s;
    #pragma unroll
    for (int m = 0; m < 6; ++m) {
        int o = j + 64 * m;
        float a4 = fc4_b[o];
        const float4* w4 = (const float4*)(fc4_w + (size_t)o * HDIM);
        #pragma unroll
        for (int k4 = 0; k4 < HDIM / 4; ++k4) { fma4(a4, w4[k4], h2r[k4]); }
        float d = a4 - xs[o];
        ms = fmaf(d, d, ms);
    }
    #pragma unroll
    for (int o = 32; o; o >>= 1) ms += __shfl_xor(ms, o);
    if (j == 0) { mse_row[r] = ms; kld_row[r] = ks; }
}

// ---------------- Kernel 2: FUSED routing ------------------------------------------------
// Round-5 arithmetic exactly, restructured for register liveness: phase 2 + epilogue run
// as TWO independent 4-query groups, each carried to completion (logits -> softmax ->
// cumsum -> sampling -> stores -> log-prob) before the next begins. Peak live set drops
// from {P[8],c[8],M} (~68 VGPR) to {P[4],c[4],M} (~56) -> below the 64-reg 8-waves/SIMD
// cliff, WITHOUT launch-bounds pressure (which spilled in rounds 3/4). embT is re-read
// per group (L2-resident, FETCH unaffected). Per-query op order is bit-identical.
__global__ __launch_bounds__(256) void route_kernel(
    const float* __restrict__ contexts, const float* __restrict__ ctx_wP, const float* __restrict__ ctx_b,
    const float* __restrict__ embT, const int* __restrict__ agent_num, const float* __restrict__ rand_u,
    const float* __restrict__ mse_row, const float* __restrict__ kld_row,
    float* __restrict__ out_sel, float* __restrict__ out_lp, float* __restrict__ out_loss)
{
    __shared__ __align__(16) float lds[4][1536];         // x-tile, e-strip overlays: 24 KB

    const int tid = threadIdx.x;
    const int lane = tid & 63;
    const int widx = tid >> 6;
    const int l0 = lane << 2;

    const int g = blockIdx.x * 4 + widx;                 // wave id [0, 8192)
    const int q0 = __builtin_amdgcn_readfirstlane(g << 3);
    float* myl = lds[widx];

    // ---- stage 8 context rows (6 KB contiguous, fully coalesced vector loads) ----
    {
        float4* xls = (float4*)myl;
        const float4* cbase = (const float4*)contexts + (size_t)q0 * (D_CTX / 4);
        #pragma unroll
        for (int it = 0; it < 6; ++it) {
            int f = lane + it * 64;                      // [0, 384)
            xls[f] = cbase[f];
        }
    }

    // ---- fold in vae_loss finalize (wave 0 only) ----
    if (g == 0) {
        int rr = lane * 4;
        float ms = mse_row[rr] + mse_row[rr + 1] + mse_row[rr + 2] + mse_row[rr + 3];
        float ks = kld_row[rr] + kld_row[rr + 1] + kld_row[rr + 2] + kld_row[rr + 3];
        #pragma unroll
        for (int o = 32; o; o >>= 1) { ms += __shfl_xor(ms, o); ks += __shfl_xor(ks, o); }
        if (lane == 0) out_loss[0] = ms / 98304.0f - 0.5f * (ks / 16384.0f);
    }

    // ---- agent counts: wave-uniform index -> scalar loads ----
    int Aq[8];
    #pragma unroll
    for (int q = 0; q < 8; ++q) Aq[q] = agent_num[q0 + q];

    // ---- phase 1: e_j (lane j) for 8 queries; w coalesced b128, x uniform LDS broadcast,
    //      packed fp32 FMAs (even/odd k split) ----
    const float bj = ctx_b[lane];
    v2f acc[8];
    #pragma unroll
    for (int q = 0; q < 8; ++q) acc[q] = mk2(bj, 0.0f);
    {
        const float4* wp = (const float4*)ctx_wP;
        const float4* xls = (const float4*)myl;
        #pragma unroll 2
        for (int k4 = 0; k4 < D_CTX / 4; ++k4) {
            float4 w = wp[k4 * HDIM + lane];             // lane-coalesced 1 KB load
            v2f w01 = mk2(w.x, w.y), w23 = mk2(w.z, w.w);
            #pragma unroll
            for (int q = 0; q < 8; ++q) {
                float4 xv = xls[q * 48 + k4];            // uniform broadcast ds_read_b128
                acc[q] = __builtin_elementwise_fma(w01, mk2(xv.x, xv.y), acc[q]);
                acc[q] = __builtin_elementwise_fma(w23, mk2(xv.z, xv.w), acc[q]);
            }
        }
    }
    {
        float e[8];
        #pragma unroll
        for (int q = 0; q < 8; ++q) e[q] = acc[q].x + acc[q].y;
        #pragma unroll
        for (int q = 0; q < 8; ++q) {
            float s = bc63(wave_iscan(e[q] * e[q]));     // wave sum via DPP -> SGPR
            e[q] *= 1.0f / fmaxf(sqrtf(s), 1e-12f);
            myl[q * HDIM + lane] = e[q];                 // e-strip overlays dead x region
        }
    }

    // ---- phases 2..5 in two independent 4-query groups (register liveness) ----
    #pragma unroll
    for (int grp = 0; grp < 2; ++grp) {
        // -- logits: lane's 4 llms x 4 queries; packed fp32, op_sel e-broadcast --
        v2f Pa[4], Pb[4];                                // (l0,l0+1) and (l0+2,l0+3)
        #pragma unroll
        for (int qq = 0; qq < 4; ++qq) { Pa[qq] = mk2(0.0f, 0.0f); Pb[qq] = mk2(0.0f, 0.0f); }

        #pragma unroll 2
        for (int j4 = 0; j4 < HDIM / 4; ++j4) {
            float4 M0 = *(const float4*)(embT + (size_t)(j4 * 4 + 0) * N_L + l0);  // coalesced
            float4 M1 = *(const float4*)(embT + (size_t)(j4 * 4 + 1) * N_L + l0);
            float4 M2 = *(const float4*)(embT + (size_t)(j4 * 4 + 2) * N_L + l0);
            float4 M3 = *(const float4*)(embT + (size_t)(j4 * 4 + 3) * N_L + l0);
            v2f m0a = mk2(M0.x, M0.y), m0b = mk2(M0.z, M0.w);
            v2f m1a = mk2(M1.x, M1.y), m1b = mk2(M1.z, M1.w);
            v2f m2a = mk2(M2.x, M2.y), m2b = mk2(M2.z, M2.w);
            v2f m3a = mk2(M3.x, M3.y), m3b = mk2(M3.z, M3.w);
            #pragma unroll
            for (int qq = 0; qq < 4; ++qq) {
                int q = grp * 4 + qq;
                float4 ev = *(const float4*)(myl + q * HDIM + j4 * 4);  // uniform broadcast
                v2f e01 = mk2(ev.x, ev.y), e23 = mk2(ev.z, ev.w);
                // per-component order identical to prior rounds
                pk_fma_lo(Pa[qq], m0a, e01);
                pk_fma_hi(Pa[qq], m1a, e01);
                pk_fma_lo(Pa[qq], m2a, e23);
                pk_fma_hi(Pa[qq], m3a, e23);
                pk_fma_lo(Pb[qq], m0b, e01);
                pk_fma_hi(Pb[qq], m1b, e01);
                pk_fma_lo(Pb[qq], m2b, e23);
                pk_fma_hi(Pb[qq], m3b, e23);
            }
        }

        // -- softmax + inclusive cumsum fused per query (DPP; same per-component order) --
        float c0[4], c1[4], c2[4], c3[4];
        #pragma unroll
        for (int kk = 0; kk < 4; ++kk) {
            float px = Pa[kk].x, py = Pa[kk].y, pz = Pb[kk].x, pw = Pb[kk].y;
            float m = fmaxf(fmaxf(px, py), fmaxf(pz, pw));
            m = bc63(wave_max_l63(m));                   // exact wave max
            px = expf(px - m); py = expf(py - m);
            pz = expf(pz - m); pw = expf(pw - m);
            float s = bc63(wave_iscan(px + py + pz + pw));
            float inv = 1.0f / s;
            px *= inv; py *= inv; pz *= inv; pw *= inv;
            c0[kk] = px; c1[kk] = c0[kk] + py; c2[kk] = c1[kk] + pz;
            float p3 = c2[kk] + pw;
            float t = wave_iscan(p3);
            float base = t - p3;
            c0[kk] += base; c1[kk] += base; c2[kk] += base; c3[kk] = p3 + base;
        }

        // -- sampling: ballot+popcount on cumsum; u via wave-uniform scalar load --
        unsigned nib[4] = {0, 0, 0, 0};
        #pragma unroll
        for (int i = 0; i < MAXA; ++i) {
            #pragma unroll
            for (int kk = 0; kk < 4; ++kk) {
                int k = grp * 4 + kk;
                if (i < Aq[k]) {                   // wave-uniform scalar branch
                    float u = rand_u[(size_t)i * N_Q + q0 + k];   // uniform -> s_load
                    unsigned long long b0 = __ballot(c0[kk] <= u);
                    unsigned long long b1 = __ballot(c1[kk] <= u);
                    unsigned long long b2 = __ballot(c2[kk] <= u);
                    unsigned long long b3 = __ballot(c3[kk] <= u);
                    int loc = __popcll(b0) + __popcll(b1) + __popcll(b2) + __popcll(b3);
                    int sel = (loc >= N_L) ? 0 : loc;  // numpy argmax(all-False) == 0
                    unsigned d = (unsigned)(sel - l0);
                    if (d < 4u) nib[kk] += 1u << (4 * d);
                }
            }
        }

        // -- row stores + log-prob terms; p reconstructed from cumsum deltas --
        float st[4];
        #pragma unroll
        for (int kk = 0; kk < 4; ++kk) {
            int k = grp * 4 + kk;
            int n0 = nib[kk] & 15, n1 = (nib[kk] >> 4) & 15,
                n2 = (nib[kk] >> 8) & 15, n3 = (nib[kk] >> 12) & 15;
            float4 rowv = make_float4((float)n0, (float)n1, (float)n2, (float)n3);
            *(((float4*)(out_sel + (size_t)(q0 + k) * N_L)) + lane) = rowv;
            float base = __shfl_up(c3[kk], 1);
            base = (lane == 0) ? 0.0f : base;
            float px = c0[kk] - base, py = c1[kk] - c0[kk],
                  pz = c2[kk] - c1[kk], pw = c3[kk] - c2[kk];
            float tm = 0.0f;
            if (n0) tm += (float)n0 * logf(px) - lgfact(n0);
            if (n1) tm += (float)n1 * logf(py) - lgfact(n1);
            if (n2) tm += (float)n2 * logf(pz) - lgfact(n2);
            if (n3) tm += (float)n3 * logf(pw) - lgfact(n3);
            st[kk] = bc63(wave_iscan(tm));
        }

        if (lane < 4) {
            float rr = st[0];
            int Aa = Aq[grp * 4];
            #pragma unroll
            for (int kk = 1; kk < 4; ++kk) {
                if (lane == kk) { rr = st[kk]; Aa = Aq[grp * 4 + kk]; }
            }
            out_lp[q0 + grp * 4 + lane] = lgfact(Aa) + rr;
        }

        // keep group working sets disjoint: no cross-group hoisting by the scheduler
        __builtin_amdgcn_sched_barrier(0);
    }
}

extern "C" void kernel_launch(void* const* d_in, const int* in_sizes, int n_in,
                              void* d_out, int out_size, void* d_ws, size_t ws_size,
                              hipStream_t stream) {
    const float* llms      = (const float*)d_in[0];
    const float* contexts  = (const float*)d_in[1];
    const int*   agent_i   = (const int*)  d_in[2];
    // d_in[3] agent_num_float unused (int version + table)
    const float* fc1_w  = (const float*)d_in[4];  const float* fc1_b  = (const float*)d_in[5];
    const float* fc21_w = (const float*)d_in[6];  const float* fc21_b = (const float*)d_in[7];
    const float* fc22_w = (const float*)d_in[8];  const float* fc22_b = (const float*)d_in[9];
    const float* fc3_w  = (const float*)d_in[10]; const float* fc3_b  = (const float*)d_in[11];
    const float* fc4_w  = (const float*)d_in[12]; const float* fc4_b  = (const float*)d_in[13];
    const float* ctx_w  = (const float*)d_in[14]; const float* ctx_b  = (const float*)d_in[15];
    const float* noise  = (const float*)d_in[16]; const float* rand_u = (const float*)d_in[17];

    float* out      = (float*)d_out;
    float* out_sel  = out;                          // [65536][256]
    float* out_lp   = out + (size_t)N_Q * N_L;      // [65536]
    float* out_loss = out_lp + N_Q;                 // [1]

    float* ctx_wP   = (float*)d_ws;                 // [48][64] float4 (12288 floats)
    float* embT     = ctx_wP + D_CTX * HDIM;        // [64][256]
    float* mse_row  = embT + HDIM * N_L;            // [256]
    float* kld_row  = mse_row + N_L;                // [256]

    vae_kernel<<<N_L, 64, 0, stream>>>(llms, ctx_w, fc1_w, fc1_b, fc21_w, fc21_b, fc22_w, fc22_b,
                                       fc3_w, fc3_b, fc4_w, fc4_b, noise,
                                       ctx_wP, embT, mse_row, kld_row);
    route_kernel<<<2048, 256, 0, stream>>>(contexts, ctx_wP, ctx_b, embT, agent_i, rand_u,
                                           mse_row, kld_row, out_sel, out_lp, out_loss);
}

// Round 7
// 222.140 us; speedup vs baseline: 1.1499x; 1.0034x over previous
//
#include <hip/hip_runtime.h>

#define N_L 256
#define N_Q 65536
#define D_IN 384
#define D_CTX 192
#define HDIM 64
#define MAXA 6

typedef float v2f __attribute__((ext_vector_type(2)));

__device__ __forceinline__ v2f mk2(float a, float b) { v2f r; r.x = a; r.y = b; return r; }

__device__ __forceinline__ void fma4(float& acc, const float4& w, const float4& v) {
    acc = fmaf(w.x, v.x, acc);
    acc = fmaf(w.y, v.y, acc);
    acc = fmaf(w.z, v.z, acc);
    acc = fmaf(w.w, v.w, acc);
}

__device__ __forceinline__ float lgfact(int n) {
    // log(n!) for n in 0..6  (== gammaln(n+1))
    return (n <= 1) ? 0.0f :
           (n == 2) ? 0.6931471805599453f :
           (n == 3) ? 1.7917594692280550f :
           (n == 4) ? 3.1780538303479458f :
           (n == 5) ? 4.7874917427820460f :
                      6.5792512120101010f;
}

// ---------------- DPP wave reduction helpers (VALU pipe, no LDS traffic) ----------------
template<int CTRL, int RM, bool BC>
__device__ __forceinline__ float dppz(float x) {   // old = 0 (masked/invalid lanes contribute 0)
    return __int_as_float(__builtin_amdgcn_update_dpp(0, __float_as_int(x), CTRL, RM, 0xF, BC));
}
template<int CTRL, int RM>
__device__ __forceinline__ float dpps(float x) {   // old = x (identity for max)
    int xi = __float_as_int(x);
    return __int_as_float(__builtin_amdgcn_update_dpp(xi, xi, CTRL, RM, 0xF, false));
}
// inclusive prefix-sum across 64 lanes; lane 63 ends with the wave total
__device__ __forceinline__ float wave_iscan(float t) {
    t += dppz<0x111, 0xF, true>(t);    // row_shr:1, 0-fill
    t += dppz<0x112, 0xF, true>(t);    // row_shr:2
    t += dppz<0x114, 0xF, true>(t);    // row_shr:4
    t += dppz<0x118, 0xF, true>(t);    // row_shr:8
    t += dppz<0x142, 0xA, false>(t);   // row_bcast:15 -> rows 1,3
    t += dppz<0x143, 0xC, false>(t);   // row_bcast:31 -> rows 2,3
    return t;
}
// wave max; lane 63 ends with the full 64-lane max (exact, max is associative)
__device__ __forceinline__ float wave_max_l63(float m) {
    m = fmaxf(m, dpps<0x111, 0xF>(m));
    m = fmaxf(m, dpps<0x112, 0xF>(m));
    m = fmaxf(m, dpps<0x114, 0xF>(m));
    m = fmaxf(m, dpps<0x118, 0xF>(m));
    m = fmaxf(m, dpps<0x142, 0xA>(m));
    m = fmaxf(m, dpps<0x143, 0xC>(m));
    return m;
}
__device__ __forceinline__ float bc63(float x) {   // broadcast lane 63 via SGPR
    return __int_as_float(__builtin_amdgcn_readlane(__float_as_int(x), 63));
}
// shift the whole wave right by one lane (lane i <- lane i-1), lane 0 <- 0. DPP wave_shr:1
__device__ __forceinline__ float wave_shr1_z(float x) {
    return dppz<0x138, 0xF, true>(x);
}

// ---------------- Kernel 1: VAE + llm embT + packed ctx_w transpose + loss partials ----
__global__ __launch_bounds__(64) void vae_kernel(
    const float* __restrict__ llms, const float* __restrict__ ctx_w,
    const float* __restrict__ fc1_w, const float* __restrict__ fc1_b,
    const float* __restrict__ fc21_w, const float* __restrict__ fc21_b,
    const float* __restrict__ fc22_w, const float* __restrict__ fc22_b,
    const float* __restrict__ fc3_w, const float* __restrict__ fc3_b,
    const float* __restrict__ fc4_w, const float* __restrict__ fc4_b,
    const float* __restrict__ eps,
    float* __restrict__ ctx_wP, float* __restrict__ embT,
    float* __restrict__ mse_row, float* __restrict__ kld_row)
{
    __shared__ __align__(16) float xs[D_IN];
    __shared__ __align__(16) float hs[HDIM];
    __shared__ __align__(16) float zs[HDIM];
    __shared__ __align__(16) float h2s[HDIM];
    const int r = blockIdx.x;
    const int j = threadIdx.x;

    // side job: pack-transpose ctx_w -> ctx_wP[(k4*64+j)*4+rr] = ctx_w[j*192+k4*4+rr]
    {
        int f = r * 64 + j;                       // [0, 16384); need [0, 12288)
        if (f < D_CTX * HDIM) {
            int p = f >> 2, rr = f & 3;
            int jc = p & 63, k4 = p >> 6;
            ctx_wP[f] = ctx_w[jc * D_CTX + k4 * 4 + rr];
        }
    }

    for (int k = j; k < D_IN; k += 64) xs[k] = llms[r * D_IN + k];
    __syncthreads();

    float acc = fc1_b[j];
    {
        const float4* wr = (const float4*)(fc1_w + (size_t)j * D_IN);
        const float4* xr = (const float4*)xs;
        #pragma unroll 8
        for (int k4 = 0; k4 < D_IN / 4; ++k4) { fma4(acc, wr[k4], xr[k4]); }
    }
    float h = fmaxf(acc, 0.0f);
    hs[j] = h;
    __syncthreads();

    float mu = fc21_b[j], lv = fc22_b[j];
    {
        const float4* w1 = (const float4*)(fc21_w + (size_t)j * HDIM);
        const float4* w2 = (const float4*)(fc22_w + (size_t)j * HDIM);
        const float4* hr = (const float4*)hs;
        #pragma unroll
        for (int k4 = 0; k4 < HDIM / 4; ++k4) {
            float4 hh = hr[k4];
            fma4(mu, w1[k4], hh);
            fma4(lv, w2[k4], hh);
        }
    }
    float stdv = expf(0.5f * lv) * 0.1f;
    float z = fmaf(eps[r * HDIM + j], stdv, mu);

    float elv = expf(lv);
    float kt = (1.0f - (-4.60517018598809136f)) + lv - (mu * mu + elv) / 0.01f;
    float ks = kt;
    #pragma unroll
    for (int o = 32; o; o >>= 1) ks += __shfl_xor(ks, o);

    float zsq = z * z;
    #pragma unroll
    for (int o = 32; o; o >>= 1) zsq += __shfl_xor(zsq, o);
    float nrm = fmaxf(sqrtf(zsq), 1e-12f);
    embT[j * N_L + r] = z / nrm;                 // transposed store (one-time scatter)
    zs[j] = z;
    __syncthreads();

    float a3 = fc3_b[j];
    {
        const float4* w3 = (const float4*)(fc3_w + (size_t)j * HDIM);
        const float4* zr = (const float4*)zs;
        #pragma unroll
        for (int k4 = 0; k4 < HDIM / 4; ++k4) { fma4(a3, w3[k4], zr[k4]); }
    }
    float h2 = fmaxf(a3, 0.0f);
    h2s[j] = h2;
    __syncthreads();

    float ms = 0.0f;
    const float4* h2r = (const float4*)h2s;
    #pragma unroll
    for (int m = 0; m < 6; ++m) {
        int o = j + 64 * m;
        float a4 = fc4_b[o];
        const float4* w4 = (const float4*)(fc4_w + (size_t)o * HDIM);
        #pragma unroll
        for (int k4 = 0; k4 < HDIM / 4; ++k4) { fma4(a4, w4[k4], h2r[k4]); }
        float d = a4 - xs[o];
        ms = fmaf(d, d, ms);
    }
    #pragma unroll
    for (int o = 32; o; o >>= 1) ms += __shfl_xor(ms, o);
    if (j == 0) { mse_row[r] = ms; kld_row[r] = ks; }
}

// ---------------- Kernel 2: FUSED routing ------------------------------------------------
// Round-6 structure (two independent 4-query groups, VGPR ~40, occupancy ~48%).
// VALU-overhead round: (1) phase-2 inline-asm pk_fma replaced with
// __builtin_elementwise_fma + splat v2f — LLVM folds the splat into op_sel on
// v_pk_fma_f32, removing asm operand-marshaling movs and letting the scheduler fold
// mk2 splits; per-component accumulation order unchanged. (2) expf/logf -> __expf/__logf
// (v_exp_f32/v_log_f32, ~1e-7 rel err — below the fp32-order noise the tolerance already
// absorbs). (3) __shfl_up -> DPP wave_shr:1 (drops an LDS bpermute per query).
__global__ __launch_bounds__(256) void route_kernel(
    const float* __restrict__ contexts, const float* __restrict__ ctx_wP, const float* __restrict__ ctx_b,
    const float* __restrict__ embT, const int* __restrict__ agent_num, const float* __restrict__ rand_u,
    const float* __restrict__ mse_row, const float* __restrict__ kld_row,
    float* __restrict__ out_sel, float* __restrict__ out_lp, float* __restrict__ out_loss)
{
    __shared__ __align__(16) float lds[4][1536];         // x-tile, e-strip overlays: 24 KB

    const int tid = threadIdx.x;
    const int lane = tid & 63;
    const int widx = tid >> 6;
    const int l0 = lane << 2;

    const int g = blockIdx.x * 4 + widx;                 // wave id [0, 8192)
    const int q0 = __builtin_amdgcn_readfirstlane(g << 3);
    float* myl = lds[widx];

    // ---- stage 8 context rows (6 KB contiguous, fully coalesced vector loads) ----
    {
        float4* xls = (float4*)myl;
        const float4* cbase = (const float4*)contexts + (size_t)q0 * (D_CTX / 4);
        #pragma unroll
        for (int it = 0; it < 6; ++it) {
            int f = lane + it * 64;                      // [0, 384)
            xls[f] = cbase[f];
        }
    }

    // ---- fold in vae_loss finalize (wave 0 only) ----
    if (g == 0) {
        int rr = lane * 4;
        float ms = mse_row[rr] + mse_row[rr + 1] + mse_row[rr + 2] + mse_row[rr + 3];
        float ks = kld_row[rr] + kld_row[rr + 1] + kld_row[rr + 2] + kld_row[rr + 3];
        #pragma unroll
        for (int o = 32; o; o >>= 1) { ms += __shfl_xor(ms, o); ks += __shfl_xor(ks, o); }
        if (lane == 0) out_loss[0] = ms / 98304.0f - 0.5f * (ks / 16384.0f);
    }

    // ---- agent counts: wave-uniform index -> scalar loads ----
    int Aq[8];
    #pragma unroll
    for (int q = 0; q < 8; ++q) Aq[q] = agent_num[q0 + q];

    // ---- phase 1: e_j (lane j) for 8 queries; w coalesced b128, x uniform LDS broadcast,
    //      packed fp32 FMAs (even/odd k split) ----
    const float bj = ctx_b[lane];
    v2f acc[8];
    #pragma unroll
    for (int q = 0; q < 8; ++q) acc[q] = mk2(bj, 0.0f);
    {
        const float4* wp = (const float4*)ctx_wP;
        const float4* xls = (const float4*)myl;
        #pragma unroll 2
        for (int k4 = 0; k4 < D_CTX / 4; ++k4) {
            float4 w = wp[k4 * HDIM + lane];             // lane-coalesced 1 KB load
            v2f w01 = mk2(w.x, w.y), w23 = mk2(w.z, w.w);
            #pragma unroll
            for (int q = 0; q < 8; ++q) {
                float4 xv = xls[q * 48 + k4];            // uniform broadcast ds_read_b128
                acc[q] = __builtin_elementwise_fma(w01, mk2(xv.x, xv.y), acc[q]);
                acc[q] = __builtin_elementwise_fma(w23, mk2(xv.z, xv.w), acc[q]);
            }
        }
    }
    {
        float e[8];
        #pragma unroll
        for (int q = 0; q < 8; ++q) e[q] = acc[q].x + acc[q].y;
        #pragma unroll
        for (int q = 0; q < 8; ++q) {
            float s = bc63(wave_iscan(e[q] * e[q]));     // wave sum via DPP -> SGPR
            e[q] *= 1.0f / fmaxf(sqrtf(s), 1e-12f);
            myl[q * HDIM + lane] = e[q];                 // e-strip overlays dead x region
        }
    }

    // ---- phases 2..5 in two independent 4-query groups (register liveness) ----
    #pragma unroll
    for (int grp = 0; grp < 2; ++grp) {
        // -- logits: lane's 4 llms x 4 queries; packed fp32 via builtin, splat -> op_sel --
        v2f Pa[4], Pb[4];                                // (l0,l0+1) and (l0+2,l0+3)
        #pragma unroll
        for (int qq = 0; qq < 4; ++qq) { Pa[qq] = mk2(0.0f, 0.0f); Pb[qq] = mk2(0.0f, 0.0f); }

        #pragma unroll 2
        for (int j4 = 0; j4 < HDIM / 4; ++j4) {
            float4 M0 = *(const float4*)(embT + (size_t)(j4 * 4 + 0) * N_L + l0);  // coalesced
            float4 M1 = *(const float4*)(embT + (size_t)(j4 * 4 + 1) * N_L + l0);
            float4 M2 = *(const float4*)(embT + (size_t)(j4 * 4 + 2) * N_L + l0);
            float4 M3 = *(const float4*)(embT + (size_t)(j4 * 4 + 3) * N_L + l0);
            v2f m0a = mk2(M0.x, M0.y), m0b = mk2(M0.z, M0.w);
            v2f m1a = mk2(M1.x, M1.y), m1b = mk2(M1.z, M1.w);
            v2f m2a = mk2(M2.x, M2.y), m2b = mk2(M2.z, M2.w);
            v2f m3a = mk2(M3.x, M3.y), m3b = mk2(M3.z, M3.w);
            #pragma unroll
            for (int qq = 0; qq < 4; ++qq) {
                int q = grp * 4 + qq;
                float4 ev = *(const float4*)(myl + q * HDIM + j4 * 4);  // uniform broadcast
                v2f ex = mk2(ev.x, ev.x), ey = mk2(ev.y, ev.y);
                v2f ez = mk2(ev.z, ev.z), ew = mk2(ev.w, ev.w);
                // per-component order identical to prior rounds:
                // P.c += M0.c*ev.x; += M1.c*ev.y; += M2.c*ev.z; += M3.c*ev.w
                Pa[qq] = __builtin_elementwise_fma(m0a, ex, Pa[qq]);
                Pa[qq] = __builtin_elementwise_fma(m1a, ey, Pa[qq]);
                Pa[qq] = __builtin_elementwise_fma(m2a, ez, Pa[qq]);
                Pa[qq] = __builtin_elementwise_fma(m3a, ew, Pa[qq]);
                Pb[qq] = __builtin_elementwise_fma(m0b, ex, Pb[qq]);
                Pb[qq] = __builtin_elementwise_fma(m1b, ey, Pb[qq]);
                Pb[qq] = __builtin_elementwise_fma(m2b, ez, Pb[qq]);
                Pb[qq] = __builtin_elementwise_fma(m3b, ew, Pb[qq]);
            }
        }

        // -- softmax + inclusive cumsum fused per query (DPP; same per-component order) --
        float c0[4], c1[4], c2[4], c3[4];
        #pragma unroll
        for (int kk = 0; kk < 4; ++kk) {
            float px = Pa[kk].x, py = Pa[kk].y, pz = Pb[kk].x, pw = Pb[kk].y;
            float m = fmaxf(fmaxf(px, py), fmaxf(pz, pw));
            m = bc63(wave_max_l63(m));                   // exact wave max
            px = __expf(px - m); py = __expf(py - m);
            pz = __expf(pz - m); pw = __expf(pw - m);
            float s = bc63(wave_iscan(px + py + pz + pw));
            float inv = 1.0f / s;
            px *= inv; py *= inv; pz *= inv; pw *= inv;
            c0[kk] = px; c1[kk] = c0[kk] + py; c2[kk] = c1[kk] + pz;
            float p3 = c2[kk] + pw;
            float t = wave_iscan(p3);
            float base = t - p3;
            c0[kk] += base; c1[kk] += base; c2[kk] += base; c3[kk] = p3 + base;
        }

        // -- sampling: ballot+popcount on cumsum; u via wave-uniform scalar load --
        unsigned nib[4] = {0, 0, 0, 0};
        #pragma unroll
        for (int i = 0; i < MAXA; ++i) {
            #pragma unroll
            for (int kk = 0; kk < 4; ++kk) {
                int k = grp * 4 + kk;
                if (i < Aq[k]) {                   // wave-uniform scalar branch
                    float u = rand_u[(size_t)i * N_Q + q0 + k];   // uniform -> s_load
                    unsigned long long b0 = __ballot(c0[kk] <= u);
                    unsigned long long b1 = __ballot(c1[kk] <= u);
                    unsigned long long b2 = __ballot(c2[kk] <= u);
                    unsigned long long b3 = __ballot(c3[kk] <= u);
                    int loc = __popcll(b0) + __popcll(b1) + __popcll(b2) + __popcll(b3);
                    int sel = (loc >= N_L) ? 0 : loc;  // numpy argmax(all-False) == 0
                    unsigned d = (unsigned)(sel - l0);
                    if (d < 4u) nib[kk] += 1u << (4 * d);
                }
            }
        }

        // -- row stores + log-prob terms; p reconstructed from cumsum deltas --
        float st[4];
        #pragma unroll
        for (int kk = 0; kk < 4; ++kk) {
            int k = grp * 4 + kk;
            int n0 = nib[kk] & 15, n1 = (nib[kk] >> 4) & 15,
                n2 = (nib[kk] >> 8) & 15, n3 = (nib[kk] >> 12) & 15;
            float4 rowv = make_float4((float)n0, (float)n1, (float)n2, (float)n3);
            *(((float4*)(out_sel + (size_t)(q0 + k) * N_L)) + lane) = rowv;
            float base = wave_shr1_z(c3[kk]);            // lane i <- lane i-1, lane 0 <- 0
            float px = c0[kk] - base, py = c1[kk] - c0[kk],
                  pz = c2[kk] - c1[kk], pw = c3[kk] - c2[kk];
            float tm = 0.0f;
            if (n0) tm += (float)n0 * __logf(px) - lgfact(n0);
            if (n1) tm += (float)n1 * __logf(py) - lgfact(n1);
            if (n2) tm += (float)n2 * __logf(pz) - lgfact(n2);
            if (n3) tm += (float)n3 * __logf(pw) - lgfact(n3);
            st[kk] = bc63(wave_iscan(tm));
        }

        if (lane < 4) {
            float rr = st[0];
            int Aa = Aq[grp * 4];
            #pragma unroll
            for (int kk = 1; kk < 4; ++kk) {
                if (lane == kk) { rr = st[kk]; Aa = Aq[grp * 4 + kk]; }
            }
            out_lp[q0 + grp * 4 + lane] = lgfact(Aa) + rr;
        }

        // keep group working sets disjoint: no cross-group hoisting by the scheduler
        __builtin_amdgcn_sched_barrier(0);
    }
}

extern "C" void kernel_launch(void* const* d_in, const int* in_sizes, int n_in,
                              void* d_out, int out_size, void* d_ws, size_t ws_size,
                              hipStream_t stream) {
    const float* llms      = (const float*)d_in[0];
    const float* contexts  = (const float*)d_in[1];
    const int*   agent_i   = (const int*)  d_in[2];
    // d_in[3] agent_num_float unused (int version + table)
    const float* fc1_w  = (const float*)d_in[4];  const float* fc1_b  = (const float*)d_in[5];
    const float* fc21_w = (const float*)d_in[6];  const float* fc21_b = (const float*)d_in[7];
    const float* fc22_w = (const float*)d_in[8];  const float* fc22_b = (const float*)d_in[9];
    const float* fc3_w  = (const float*)d_in[10]; const float* fc3_b  = (const float*)d_in[11];
    const float* fc4_w  = (const float*)d_in[12]; const float* fc4_b  = (const float*)d_in[13];
    const float* ctx_w  = (const float*)d_in[14]; const float* ctx_b  = (const float*)d_in[15];
    const float* noise  = (const float*)d_in[16]; const float* rand_u = (const float*)d_in[17];

    float* out      = (float*)d_out;
    float* out_sel  = out;                          // [65536][256]
    float* out_lp   = out + (size_t)N_Q * N_L;      // [65536]
    float* out_loss = out_lp + N_Q;                 // [1]

    float* ctx_wP   = (float*)d_ws;                 // [48][64] float4 (12288 floats)
    float* embT     = ctx_wP + D_CTX * HDIM;        // [64][256]
    float* mse_row  = embT + HDIM * N_L;            // [256]
    float* kld_row  = mse_row + N_L;                // [256]

    vae_kernel<<<N_L, 64, 0, stream>>>(llms, ctx_w, fc1_w, fc1_b, fc21_w, fc21_b, fc22_w, fc22_b,
                                       fc3_w, fc3_b, fc4_w, fc4_b, noise,
                                       ctx_wP, embT, mse_row, kld_row);
    route_kernel<<<2048, 256, 0, stream>>>(contexts, ctx_wP, ctx_b, embT, agent_i, rand_u,
                                           mse_row, kld_row, out_sel, out_lp, out_loss);
}

// Round 8
// 217.515 us; speedup vs baseline: 1.1744x; 1.0213x over previous
//
#include <hip/hip_runtime.h>

#define N_L 256
#define N_Q 65536
#define D_IN 384
#define D_CTX 192
#define HDIM 64
#define MAXA 6

typedef float v2f __attribute__((ext_vector_type(2)));

__device__ __forceinline__ v2f mk2(float a, float b) { v2f r; r.x = a; r.y = b; return r; }

__device__ __forceinline__ void fma4(float& acc, const float4& w, const float4& v) {
    acc = fmaf(w.x, v.x, acc);
    acc = fmaf(w.y, v.y, acc);
    acc = fmaf(w.z, v.z, acc);
    acc = fmaf(w.w, v.w, acc);
}

__device__ __forceinline__ float lgfact(int n) {
    // log(n!) for n in 0..6  (== gammaln(n+1))
    return (n <= 1) ? 0.0f :
           (n == 2) ? 0.6931471805599453f :
           (n == 3) ? 1.7917594692280550f :
           (n == 4) ? 3.1780538303479458f :
           (n == 5) ? 4.7874917427820460f :
                      6.5792512120101010f;
}

// ---------------- DPP wave reduction helpers (VALU pipe, no LDS traffic) ----------------
template<int CTRL, int RM, bool BC>
__device__ __forceinline__ float dppz(float x) {   // old = 0 (masked/invalid lanes contribute 0)
    return __int_as_float(__builtin_amdgcn_update_dpp(0, __float_as_int(x), CTRL, RM, 0xF, BC));
}
template<int CTRL, int RM>
__device__ __forceinline__ float dpps(float x) {   // old = x (identity for max)
    int xi = __float_as_int(x);
    return __int_as_float(__builtin_amdgcn_update_dpp(xi, xi, CTRL, RM, 0xF, false));
}
// inclusive prefix-sum across 64 lanes; lane 63 ends with the wave total
__device__ __forceinline__ float wave_iscan(float t) {
    t += dppz<0x111, 0xF, true>(t);    // row_shr:1, 0-fill
    t += dppz<0x112, 0xF, true>(t);    // row_shr:2
    t += dppz<0x114, 0xF, true>(t);    // row_shr:4
    t += dppz<0x118, 0xF, true>(t);    // row_shr:8
    t += dppz<0x142, 0xA, false>(t);   // row_bcast:15 -> rows 1,3
    t += dppz<0x143, 0xC, false>(t);   // row_bcast:31 -> rows 2,3
    return t;
}
// wave max; lane 63 ends with the full 64-lane max (exact, max is associative)
__device__ __forceinline__ float wave_max_l63(float m) {
    m = fmaxf(m, dpps<0x111, 0xF>(m));
    m = fmaxf(m, dpps<0x112, 0xF>(m));
    m = fmaxf(m, dpps<0x114, 0xF>(m));
    m = fmaxf(m, dpps<0x118, 0xF>(m));
    m = fmaxf(m, dpps<0x142, 0xA>(m));
    m = fmaxf(m, dpps<0x143, 0xC>(m));
    return m;
}
__device__ __forceinline__ float bc63(float x) {   // broadcast lane 63 via SGPR
    return __int_as_float(__builtin_amdgcn_readlane(__float_as_int(x), 63));
}
// shift the whole wave right by one lane (lane i <- lane i-1), lane 0 <- 0. DPP wave_shr:1
__device__ __forceinline__ float wave_shr1_z(float x) {
    return dppz<0x138, 0xF, true>(x);
}

// ---------------- Kernel 1: VAE + llm embT + packed ctx_w transpose + loss partials ----
// PARALLELISM PROBE: 256 threads (4 waves) per row instead of 64. fc1 splits K into 4
// wave-quarters (within-quarter order exact; quarters pairwise-summed). fc21/fc22 run
// concurrently on waves 1/2 with the exact original serial order. z/KLD/norm/embT stay
// exact on wave 0. fc3 exact on wave 1. fc4's six 64-output strips spread over 4 waves
// (only the scalar-loss reduction regroups). Grid still 256 blocks -> 4 waves/CU instead
// of 1: stage latency hidden ~4x.
__global__ __launch_bounds__(256) void vae_kernel(
    const float* __restrict__ llms, const float* __restrict__ ctx_w,
    const float* __restrict__ fc1_w, const float* __restrict__ fc1_b,
    const float* __restrict__ fc21_w, const float* __restrict__ fc21_b,
    const float* __restrict__ fc22_w, const float* __restrict__ fc22_b,
    const float* __restrict__ fc3_w, const float* __restrict__ fc3_b,
    const float* __restrict__ fc4_w, const float* __restrict__ fc4_b,
    const float* __restrict__ eps,
    float* __restrict__ ctx_wP, float* __restrict__ embT,
    float* __restrict__ mse_row, float* __restrict__ kld_row)
{
    __shared__ __align__(16) float xs[D_IN];
    __shared__ __align__(16) float pr[4][HDIM];
    __shared__ __align__(16) float hs[HDIM];
    __shared__ __align__(16) float mus[HDIM];
    __shared__ __align__(16) float lvs[HDIM];
    __shared__ __align__(16) float zs[HDIM];
    __shared__ __align__(16) float h2s[HDIM];
    __shared__ float msep[4];
    const int r = blockIdx.x;
    const int t = threadIdx.x;
    const int lane = t & 63;
    const int w = t >> 6;

    // side job: pack-transpose ctx_w -> ctx_wP (any bijective cover; blocks 0..47 hit it)
    {
        int f = r * 256 + t;                      // [0, 65536); need [0, 12288)
        if (f < D_CTX * HDIM) {
            int p = f >> 2, rr = f & 3;
            int jc = p & 63, k4 = p >> 6;
            ctx_wP[f] = ctx_w[jc * D_CTX + k4 * 4 + rr];
        }
    }

    if (t < 96) ((float4*)xs)[t] = ((const float4*)(llms + (size_t)r * D_IN))[t];
    __syncthreads();

    // ---- fc1: output j = lane; wave w owns k-quarter [96w, 96w+96) ----
    {
        float p = 0.0f;
        const float4* wr = (const float4*)(fc1_w + (size_t)lane * D_IN);
        const float4* xr = (const float4*)xs;
        #pragma unroll 8
        for (int k4 = 0; k4 < 24; ++k4) { fma4(p, wr[24 * w + k4], xr[24 * w + k4]); }
        pr[w][lane] = p;
    }
    __syncthreads();
    if (w == 0) {
        float acc = fc1_b[lane] + ((pr[0][lane] + pr[1][lane]) + (pr[2][lane] + pr[3][lane]));
        hs[lane] = fmaxf(acc, 0.0f);
    }
    __syncthreads();

    // ---- fc21 on wave 1, fc22 on wave 2 (exact original serial order per output) ----
    if (w == 1) {
        float mu = fc21_b[lane];
        const float4* w1 = (const float4*)(fc21_w + (size_t)lane * HDIM);
        const float4* hr = (const float4*)hs;
        #pragma unroll
        for (int k4 = 0; k4 < HDIM / 4; ++k4) { fma4(mu, w1[k4], hr[k4]); }
        mus[lane] = mu;
    } else if (w == 2) {
        float lv = fc22_b[lane];
        const float4* w2 = (const float4*)(fc22_w + (size_t)lane * HDIM);
        const float4* hr = (const float4*)hs;
        #pragma unroll
        for (int k4 = 0; k4 < HDIM / 4; ++k4) { fma4(lv, w2[k4], hr[k4]); }
        lvs[lane] = lv;
    }
    __syncthreads();

    // ---- wave 0: reparameterize, KLD partial, l2norm, embT store (exact original) ----
    if (w == 0) {
        float mu = mus[lane], lv = lvs[lane];
        float stdv = expf(0.5f * lv) * 0.1f;
        float z = fmaf(eps[r * HDIM + lane], stdv, mu);

        float elv = expf(lv);
        float kt = (1.0f - (-4.60517018598809136f)) + lv - (mu * mu + elv) / 0.01f;
        float ks = kt;
        #pragma unroll
        for (int o = 32; o; o >>= 1) ks += __shfl_xor(ks, o);

        float zsq = z * z;
        #pragma unroll
        for (int o = 32; o; o >>= 1) zsq += __shfl_xor(zsq, o);
        float nrm = fmaxf(sqrtf(zsq), 1e-12f);
        embT[lane * N_L + r] = z / nrm;              // transposed store (one-time scatter)
        zs[lane] = z;
        if (lane == 0) kld_row[r] = ks;
    }
    __syncthreads();

    // ---- fc3 on wave 1 (exact original serial order) ----
    if (w == 1) {
        float a3 = fc3_b[lane];
        const float4* w3 = (const float4*)(fc3_w + (size_t)lane * HDIM);
        const float4* zr = (const float4*)zs;
        #pragma unroll
        for (int k4 = 0; k4 < HDIM / 4; ++k4) { fma4(a3, w3[k4], zr[k4]); }
        h2s[lane] = fmaxf(a3, 0.0f);
    }
    __syncthreads();

    // ---- fc4: waves take m-strips: w0:{0,4} w1:{1,5} w2:{2} w3:{3} ----
    {
        float ms = 0.0f;
        const float4* h2r = (const float4*)h2s;
        int mcount = (w < 2) ? 2 : 1;
        for (int i = 0; i < mcount; ++i) {
            int m = w + 4 * i;
            int o = lane + 64 * m;
            float a4 = fc4_b[o];
            const float4* w4 = (const float4*)(fc4_w + (size_t)o * HDIM);
            #pragma unroll
            for (int k4 = 0; k4 < HDIM / 4; ++k4) { fma4(a4, w4[k4], h2r[k4]); }
            float d = a4 - xs[o];
            ms = fmaf(d, d, ms);
        }
        #pragma unroll
        for (int o = 32; o; o >>= 1) ms += __shfl_xor(ms, o);
        if (lane == 0) msep[w] = ms;
    }
    __syncthreads();
    if (t == 0) mse_row[r] = (msep[0] + msep[1]) + (msep[2] + msep[3]);
}

// ---------------- Kernel 2: FUSED routing (byte-identical to round 7, 103 us) -----------
__global__ __launch_bounds__(256) void route_kernel(
    const float* __restrict__ contexts, const float* __restrict__ ctx_wP, const float* __restrict__ ctx_b,
    const float* __restrict__ embT, const int* __restrict__ agent_num, const float* __restrict__ rand_u,
    const float* __restrict__ mse_row, const float* __restrict__ kld_row,
    float* __restrict__ out_sel, float* __restrict__ out_lp, float* __restrict__ out_loss)
{
    __shared__ __align__(16) float lds[4][1536];         // x-tile, e-strip overlays: 24 KB

    const int tid = threadIdx.x;
    const int lane = tid & 63;
    const int widx = tid >> 6;
    const int l0 = lane << 2;

    const int g = blockIdx.x * 4 + widx;                 // wave id [0, 8192)
    const int q0 = __builtin_amdgcn_readfirstlane(g << 3);
    float* myl = lds[widx];

    // ---- stage 8 context rows (6 KB contiguous, fully coalesced vector loads) ----
    {
        float4* xls = (float4*)myl;
        const float4* cbase = (const float4*)contexts + (size_t)q0 * (D_CTX / 4);
        #pragma unroll
        for (int it = 0; it < 6; ++it) {
            int f = lane + it * 64;                      // [0, 384)
            xls[f] = cbase[f];
        }
    }

    // ---- fold in vae_loss finalize (wave 0 only) ----
    if (g == 0) {
        int rr = lane * 4;
        float ms = mse_row[rr] + mse_row[rr + 1] + mse_row[rr + 2] + mse_row[rr + 3];
        float ks = kld_row[rr] + kld_row[rr + 1] + kld_row[rr + 2] + kld_row[rr + 3];
        #pragma unroll
        for (int o = 32; o; o >>= 1) { ms += __shfl_xor(ms, o); ks += __shfl_xor(ks, o); }
        if (lane == 0) out_loss[0] = ms / 98304.0f - 0.5f * (ks / 16384.0f);
    }

    // ---- agent counts: wave-uniform index -> scalar loads ----
    int Aq[8];
    #pragma unroll
    for (int q = 0; q < 8; ++q) Aq[q] = agent_num[q0 + q];

    // ---- phase 1: e_j (lane j) for 8 queries; w coalesced b128, x uniform LDS broadcast,
    //      packed fp32 FMAs (even/odd k split) ----
    const float bj = ctx_b[lane];
    v2f acc[8];
    #pragma unroll
    for (int q = 0; q < 8; ++q) acc[q] = mk2(bj, 0.0f);
    {
        const float4* wp = (const float4*)ctx_wP;
        const float4* xls = (const float4*)myl;
        #pragma unroll 2
        for (int k4 = 0; k4 < D_CTX / 4; ++k4) {
            float4 w = wp[k4 * HDIM + lane];             // lane-coalesced 1 KB load
            v2f w01 = mk2(w.x, w.y), w23 = mk2(w.z, w.w);
            #pragma unroll
            for (int q = 0; q < 8; ++q) {
                float4 xv = xls[q * 48 + k4];            // uniform broadcast ds_read_b128
                acc[q] = __builtin_elementwise_fma(w01, mk2(xv.x, xv.y), acc[q]);
                acc[q] = __builtin_elementwise_fma(w23, mk2(xv.z, xv.w), acc[q]);
            }
        }
    }
    {
        float e[8];
        #pragma unroll
        for (int q = 0; q < 8; ++q) e[q] = acc[q].x + acc[q].y;
        #pragma unroll
        for (int q = 0; q < 8; ++q) {
            float s = bc63(wave_iscan(e[q] * e[q]));     // wave sum via DPP -> SGPR
            e[q] *= 1.0f / fmaxf(sqrtf(s), 1e-12f);
            myl[q * HDIM + lane] = e[q];                 // e-strip overlays dead x region
        }
    }

    // ---- phases 2..5 in two independent 4-query groups (register liveness) ----
    #pragma unroll
    for (int grp = 0; grp < 2; ++grp) {
        // -- logits: lane's 4 llms x 4 queries; packed fp32 via builtin, splat -> op_sel --
        v2f Pa[4], Pb[4];                                // (l0,l0+1) and (l0+2,l0+3)
        #pragma unroll
        for (int qq = 0; qq < 4; ++qq) { Pa[qq] = mk2(0.0f, 0.0f); Pb[qq] = mk2(0.0f, 0.0f); }

        #pragma unroll 2
        for (int j4 = 0; j4 < HDIM / 4; ++j4) {
            float4 M0 = *(const float4*)(embT + (size_t)(j4 * 4 + 0) * N_L + l0);  // coalesced
            float4 M1 = *(const float4*)(embT + (size_t)(j4 * 4 + 1) * N_L + l0);
            float4 M2 = *(const float4*)(embT + (size_t)(j4 * 4 + 2) * N_L + l0);
            float4 M3 = *(const float4*)(embT + (size_t)(j4 * 4 + 3) * N_L + l0);
            v2f m0a = mk2(M0.x, M0.y), m0b = mk2(M0.z, M0.w);
            v2f m1a = mk2(M1.x, M1.y), m1b = mk2(M1.z, M1.w);
            v2f m2a = mk2(M2.x, M2.y), m2b = mk2(M2.z, M2.w);
            v2f m3a = mk2(M3.x, M3.y), m3b = mk2(M3.z, M3.w);
            #pragma unroll
            for (int qq = 0; qq < 4; ++qq) {
                int q = grp * 4 + qq;
                float4 ev = *(const float4*)(myl + q * HDIM + j4 * 4);  // uniform broadcast
                v2f ex = mk2(ev.x, ev.x), ey = mk2(ev.y, ev.y);
                v2f ez = mk2(ev.z, ev.z), ew = mk2(ev.w, ev.w);
                // per-component order identical to prior rounds:
                // P.c += M0.c*ev.x; += M1.c*ev.y; += M2.c*ev.z; += M3.c*ev.w
                Pa[qq] = __builtin_elementwise_fma(m0a, ex, Pa[qq]);
                Pa[qq] = __builtin_elementwise_fma(m1a, ey, Pa[qq]);
                Pa[qq] = __builtin_elementwise_fma(m2a, ez, Pa[qq]);
                Pa[qq] = __builtin_elementwise_fma(m3a, ew, Pa[qq]);
                Pb[qq] = __builtin_elementwise_fma(m0b, ex, Pb[qq]);
                Pb[qq] = __builtin_elementwise_fma(m1b, ey, Pb[qq]);
                Pb[qq] = __builtin_elementwise_fma(m2b, ez, Pb[qq]);
                Pb[qq] = __builtin_elementwise_fma(m3b, ew, Pb[qq]);
            }
        }

        // -- softmax + inclusive cumsum fused per query (DPP; same per-component order) --
        float c0[4], c1[4], c2[4], c3[4];
        #pragma unroll
        for (int kk = 0; kk < 4; ++kk) {
            float px = Pa[kk].x, py = Pa[kk].y, pz = Pb[kk].x, pw = Pb[kk].y;
            float m = fmaxf(fmaxf(px, py), fmaxf(pz, pw));
            m = bc63(wave_max_l63(m));                   // exact wave max
            px = __expf(px - m); py = __expf(py - m);
            pz = __expf(pz - m); pw = __expf(pw - m);
            float s = bc63(wave_iscan(px + py + pz + pw));
            float inv = 1.0f / s;
            px *= inv; py *= inv; pz *= inv; pw *= inv;
            c0[kk] = px; c1[kk] = c0[kk] + py; c2[kk] = c1[kk] + pz;
            float p3 = c2[kk] + pw;
            float t = wave_iscan(p3);
            float base = t - p3;
            c0[kk] += base; c1[kk] += base; c2[kk] += base; c3[kk] = p3 + base;
        }

        // -- sampling: ballot+popcount on cumsum; u via wave-uniform scalar load --
        unsigned nib[4] = {0, 0, 0, 0};
        #pragma unroll
        for (int i = 0; i < MAXA; ++i) {
            #pragma unroll
            for (int kk = 0; kk < 4; ++kk) {
                int k = grp * 4 + kk;
                if (i < Aq[k]) {                   // wave-uniform scalar branch
                    float u = rand_u[(size_t)i * N_Q + q0 + k];   // uniform -> s_load
                    unsigned long long b0 = __ballot(c0[kk] <= u);
                    unsigned long long b1 = __ballot(c1[kk] <= u);
                    unsigned long long b2 = __ballot(c2[kk] <= u);
                    unsigned long long b3 = __ballot(c3[kk] <= u);
                    int loc = __popcll(b0) + __popcll(b1) + __popcll(b2) + __popcll(b3);
                    int sel = (loc >= N_L) ? 0 : loc;  // numpy argmax(all-False) == 0
                    unsigned d = (unsigned)(sel - l0);
                    if (d < 4u) nib[kk] += 1u << (4 * d);
                }
            }
        }

        // -- row stores + log-prob terms; p reconstructed from cumsum deltas --
        float st[4];
        #pragma unroll
        for (int kk = 0; kk < 4; ++kk) {
            int k = grp * 4 + kk;
            int n0 = nib[kk] & 15, n1 = (nib[kk] >> 4) & 15,
                n2 = (nib[kk] >> 8) & 15, n3 = (nib[kk] >> 12) & 15;
            float4 rowv = make_float4((float)n0, (float)n1, (float)n2, (float)n3);
            *(((float4*)(out_sel + (size_t)(q0 + k) * N_L)) + lane) = rowv;
            float base = wave_shr1_z(c3[kk]);            // lane i <- lane i-1, lane 0 <- 0
            float px = c0[kk] - base, py = c1[kk] - c0[kk],
                  pz = c2[kk] - c1[kk], pw = c3[kk] - c2[kk];
            float tm = 0.0f;
            if (n0) tm += (float)n0 * __logf(px) - lgfact(n0);
            if (n1) tm += (float)n1 * __logf(py) - lgfact(n1);
            if (n2) tm += (float)n2 * __logf(pz) - lgfact(n2);
            if (n3) tm += (float)n3 * __logf(pw) - lgfact(n3);
            st[kk] = bc63(wave_iscan(tm));
        }

        if (lane < 4) {
            float rr = st[0];
            int Aa = Aq[grp * 4];
            #pragma unroll
            for (int kk = 1; kk < 4; ++kk) {
                if (lane == kk) { rr = st[kk]; Aa = Aq[grp * 4 + kk]; }
            }
            out_lp[q0 + grp * 4 + lane] = lgfact(Aa) + rr;
        }

        // keep group working sets disjoint: no cross-group hoisting by the scheduler
        __builtin_amdgcn_sched_barrier(0);
    }
}

extern "C" void kernel_launch(void* const* d_in, const int* in_sizes, int n_in,
                              void* d_out, int out_size, void* d_ws, size_t ws_size,
                              hipStream_t stream) {
    const float* llms      = (const float*)d_in[0];
    const float* contexts  = (const float*)d_in[1];
    const int*   agent_i   = (const int*)  d_in[2];
    // d_in[3] agent_num_float unused (int version + table)
    const float* fc1_w  = (const float*)d_in[4];  const float* fc1_b  = (const float*)d_in[5];
    const float* fc21_w = (const float*)d_in[6];  const float* fc21_b = (const float*)d_in[7];
    const float* fc22_w = (const float*)d_in[8];  const float* fc22_b = (const float*)d_in[9];
    const float* fc3_w  = (const float*)d_in[10]; const float* fc3_b  = (const float*)d_in[11];
    const float* fc4_w  = (const float*)d_in[12]; const float* fc4_b  = (const float*)d_in[13];
    const float* ctx_w  = (const float*)d_in[14]; const float* ctx_b  = (const float*)d_in[15];
    const float* noise  = (const float*)d_in[16]; const float* rand_u = (const float*)d_in[17];

    float* out      = (float*)d_out;
    float* out_sel  = out;                          // [65536][256]
    float* out_lp   = out + (size_t)N_Q * N_L;      // [65536]
    float* out_loss = out_lp + N_Q;                 // [1]

    float* ctx_wP   = (float*)d_ws;                 // [48][64] float4 (12288 floats)
    float* embT     = ctx_wP + D_CTX * HDIM;        // [64][256]
    float* mse_row  = embT + HDIM * N_L;            // [256]
    float* kld_row  = mse_row + N_L;                // [256]

    vae_kernel<<<N_L, 256, 0, stream>>>(llms, ctx_w, fc1_w, fc1_b, fc21_w, fc21_b, fc22_w, fc22_b,
                                        fc3_w, fc3_b, fc4_w, fc4_b, noise,
                                        ctx_wP, embT, mse_row, kld_row);
    route_kernel<<<2048, 256, 0, stream>>>(contexts, ctx_wP, ctx_b, embT, agent_i, rand_u,
                                           mse_row, kld_row, out_sel, out_lp, out_loss);
}